// Round 7
// baseline (427.254 us; speedup 1.0000x reference)
//
#include <hip/hip_runtime.h>
#include <hip/hip_bf16.h>

#define NN 100000
#define NE 3200000
#define FIN 256
#define F1 16
#define F2 32
#define CO 64
#define NC 1000
#define NBLK 391   /* ceil(NN/256) */
#define NPART 8
#define PSZ 12500  /* NN / NPART */
#define BK 20      /* edges per thread in pcount/bucket; 625 blocks * 256 * 20 = NE */
#define CH 16      /* chunks per partition for hist/place */

// workspace layout (float offsets) — total 11,502,080 floats = 46.0 MB
#define OFF_DINV 0
#define OFF_CUR  100352
#define OFF_DEG  200704
#define OFF_ECOL 301056
#define OFF_MISC 3501056   /* pcnt[8], pbase[8], pcur[8], pool[64]@64, bsum[512]@512 */
#define OFF_DPART 3502080
#define OFF_SPART 6702080
#define OFF_HIST 9902080   /* u32[NPART*CH*PSZ] = 1.6M */
#define OFF_H1S  3502080   /* overlays dpart (dead after place) */
#define OFF_H2S  6702080   /* overlays spart (dead after place) */
#define OFF_OUT2 3502080   /* overlays h1s (dead after gathm) */

__device__ __forceinline__ unsigned enc_f(float f) {
    unsigned u = __float_as_uint(f);
    return (u & 0x80000000u) ? ~u : (u | 0x80000000u);
}
__device__ __forceinline__ float dec_f(unsigned u) {
    return (u & 0x80000000u) ? __uint_as_float(u & 0x7fffffffu) : __uint_as_float(~u);
}

// ---------- K0a: partition edge counts (ballot-based, no LDS) ----------
__global__ __launch_bounds__(256) void k_pcount(const int* __restrict__ ei,
                                                unsigned* __restrict__ pcnt) {
    int t = threadIdx.x, lane = t & 63;
    int base = blockIdx.x * (256 * BK) + t;
    unsigned cnt = 0;
    #pragma unroll
    for (int k = 0; k < BK; ++k) {
        int bin = (unsigned)ei[NE + base + k * 256] / PSZ;
        #pragma unroll
        for (int b = 0; b < 8; ++b) {
            unsigned long long m = __ballot(bin == b);
            if (lane == b) cnt += (unsigned)__popcll(m);
        }
    }
    if (lane < 8) atomicAdd(&pcnt[lane], cnt);
}

// ---------- K0b: 8-way exclusive prefix -> pbase, pcur ----------
__global__ void k_pscan(const unsigned* __restrict__ pcnt, unsigned* __restrict__ pbase,
                        unsigned* __restrict__ pcur) {
    int t = threadIdx.x;
    if (t < 8) {
        unsigned v = 0;
        for (int i = 0; i < t; ++i) v += pcnt[i];
        pbase[t] = v;
        pcur[t] = v;
    }
}

// ---------- K0c: bucket edges into partition-segmented (dst,src) arrays ----------
__global__ __launch_bounds__(256) void k_bucket(const int* __restrict__ ei,
                                                unsigned* __restrict__ pcur,
                                                int* __restrict__ dpart,
                                                int* __restrict__ spart) {
    int t = threadIdx.x, lane = t & 63;
    int base = blockIdx.x * (256 * BK) + t;
    int dst[BK], src[BK];
    #pragma unroll
    for (int k = 0; k < BK; ++k) {
        dst[k] = ei[NE + base + k * 256];
        src[k] = ei[base + k * 256];
    }
    unsigned long long lt = (lane == 63) ? 0x7fffffffffffffffull
                                         : ((1ull << lane) - 1ull);
    unsigned cnt = 0;
    #pragma unroll
    for (int k = 0; k < BK; ++k) {
        int bin = (unsigned)dst[k] / PSZ;
        #pragma unroll
        for (int b = 0; b < 8; ++b) {
            unsigned long long m = __ballot(bin == b);
            if (lane == b) cnt += (unsigned)__popcll(m);
        }
    }
    unsigned run = 0;
    if (lane < 8) run = atomicAdd(&pcur[lane], cnt);
    #pragma unroll
    for (int k = 0; k < BK; ++k) {
        int bin = (unsigned)dst[k] / PSZ;
        unsigned long long mym = 0;
        unsigned myrun = 0;
        #pragma unroll
        for (int b = 0; b < 8; ++b) {
            unsigned long long m = __ballot(bin == b);
            unsigned r = __shfl(run, b);
            if (bin == b) { mym = m; myrun = r; }
            if (lane == b) run += (unsigned)__popcll(m);
        }
        unsigned pos = myrun + (unsigned)__popcll(mym & lt);
        dpart[pos] = dst[k];
        spart[pos] = src[k];
    }
}

// ---------- K0d: per-chunk LDS histograms -> hist[p][c][i] ----------
__global__ __launch_bounds__(256) void k_hist(const unsigned* __restrict__ pbase,
                                              const unsigned* __restrict__ pcnt,
                                              const int* __restrict__ dpart,
                                              unsigned* __restrict__ hist) {
    __shared__ unsigned lh[PSZ];
    int p = blockIdx.x & 7;
    int c = blockIdx.x >> 3;               // 0..CH-1
    int t = threadIdx.x;
    for (int i = t; i < PSZ; i += 256) lh[i] = 0;
    __syncthreads();
    unsigned s = pbase[p], n = pcnt[p];
    unsigned c0 = s + (unsigned)(((unsigned long long)n * c) / CH);
    unsigned c1 = s + (unsigned)(((unsigned long long)n * (c + 1)) / CH);
    int pb = p * PSZ;
    for (unsigned j = c0 + t; j < c1; j += 256)
        atomicAdd(&lh[dpart[j] - pb], 1u);
    __syncthreads();
    unsigned* hrow = hist + (unsigned)(p * CH + c) * PSZ;
    for (int i = t; i < PSZ; i += 256) hrow[i] = lh[i];
}

// ---------- K0e: scan chunk counts per bin -> chunk bases (in place) + deg ----------
__global__ __launch_bounds__(256) void k_colscan(unsigned* __restrict__ hist,
                                                 unsigned* __restrict__ deg) {
    int gid = blockIdx.x * 256 + threadIdx.x;
    if (gid >= NN) return;
    int p = gid / PSZ, i = gid % PSZ;
    unsigned run = 0;
    #pragma unroll
    for (int c = 0; c < CH; ++c) {
        unsigned idx = (unsigned)(p * CH + c) * PSZ + i;
        unsigned v = hist[idx];
        hist[idx] = run;
        run += v;
    }
    deg[gid] = run;
}

// ---------- K1a: per-block degree sums ----------
__global__ void k_bsum(const unsigned* __restrict__ deg, unsigned* __restrict__ bsum) {
    __shared__ unsigned W[4];
    int t = threadIdx.x;
    int i = blockIdx.x * 256 + t;
    unsigned d = (i < NN) ? deg[i] : 0u;
    #pragma unroll
    for (int off = 1; off < 64; off <<= 1) d += __shfl_xor(d, off);
    if ((t & 63) == 0) W[t >> 6] = d;
    __syncthreads();
    if (t == 0) bsum[blockIdx.x] = W[0] + W[1] + W[2] + W[3];
}

// ---------- K1b: exclusive scan of block sums (1 block) ----------
__global__ __launch_bounds__(512) void k_bscan(unsigned* __restrict__ bsum) {
    __shared__ unsigned S[512];
    int t = threadIdx.x;
    unsigned v = (t < NBLK) ? bsum[t] : 0u;
    S[t] = v;
    __syncthreads();
    for (int off = 1; off < 512; off <<= 1) {
        unsigned u = (t >= off) ? S[t - off] : 0u;
        __syncthreads();
        S[t] += u;
        __syncthreads();
    }
    if (t < NBLK) bsum[t] = S[t] - v;   // exclusive prefix
}

// ---------- K1c: per-block scan -> cursor[i] = rowptr[i+1] (inclusive), dinv ----------
__global__ void k_cscan(const unsigned* __restrict__ deg, const unsigned* __restrict__ bsum,
                        unsigned* __restrict__ cursor, float* __restrict__ dinv) {
    __shared__ unsigned S[256];
    int t = threadIdx.x;
    int i = blockIdx.x * 256 + t;
    unsigned d = (i < NN) ? deg[i] : 0u;
    S[t] = d;
    __syncthreads();
    for (int off = 1; off < 256; off <<= 1) {
        unsigned u = (t >= off) ? S[t - off] : 0u;
        __syncthreads();
        S[t] += u;
        __syncthreads();
    }
    if (i < NN) {
        cursor[i] = bsum[blockIdx.x] + S[t];       // inclusive = rowptr[i+1]
        dinv[i] = rsqrtf((float)(d + 1u));
    }
}

// ---------- K2: place edges via LDS cursors (no global atomics) ----------
__global__ __launch_bounds__(256) void k_place(const unsigned* __restrict__ pbase,
                                               const unsigned* __restrict__ pcnt,
                                               const int* __restrict__ dpart,
                                               const int* __restrict__ spart,
                                               const unsigned* __restrict__ hist,
                                               const unsigned* __restrict__ cursor,
                                               int* __restrict__ ecol) {
    __shared__ unsigned lcur[PSZ];
    int p = blockIdx.x & 7;
    int c = blockIdx.x >> 3;
    int t = threadIdx.x;
    int pb = p * PSZ;
    const unsigned* hrow = hist + (unsigned)(p * CH + c) * PSZ;
    for (int i = t; i < PSZ; i += 256) {
        int gi = pb + i;
        unsigned rowstart = gi ? cursor[gi - 1] : 0u;
        lcur[i] = rowstart + hrow[i];
    }
    __syncthreads();
    unsigned s = pbase[p], n = pcnt[p];
    unsigned c0 = s + (unsigned)(((unsigned long long)n * c) / CH);
    unsigned c1 = s + (unsigned)(((unsigned long long)n * (c + 1)) / CH);
    for (unsigned j = c0 + t; j < c1; j += 256) {
        int dst = dpart[j];
        int src = spart[j];
        unsigned pos = atomicAdd(&lcur[dst - pb], 1u);
        ecol[pos] = src;
    }
}

// ---------- K3: h1s = (X @ W1) * dinv[row] ----------
__global__ __launch_bounds__(256) void k_gemm1(const float* __restrict__ X,
                                               const float* __restrict__ W1,
                                               const float* __restrict__ dinv,
                                               float* __restrict__ h1s) {
    __shared__ float Xs[32][257];
    __shared__ float4 Ws[1024];
    int tid = threadIdx.x;
    const float4* W14 = (const float4*)W1;
    for (int i = tid; i < 1024; i += 256) Ws[i] = W14[i];

    int rowbase = blockIdx.x * 256;
    int q  = tid >> 2;
    int cg = tid & 3;
    float4 acc[4] = {};

    for (int kt = 0; kt < 8; ++kt) {
        __syncthreads();
        #pragma unroll
        for (int it = 0; it < 8; ++it) {
            int fl = tid + it * 256;
            int rl = fl >> 3;
            int c4 = (fl & 7) << 2;
            int gr = rowbase + rl;
            float4 v = make_float4(0.f, 0.f, 0.f, 0.f);
            if (gr < NN) v = *(const float4*)(X + (size_t)gr * FIN + kt * 32 + c4);
            Xs[c4 + 0][rl] = v.x;
            Xs[c4 + 1][rl] = v.y;
            Xs[c4 + 2][rl] = v.z;
            Xs[c4 + 3][rl] = v.w;
        }
        __syncthreads();
        #pragma unroll
        for (int kk = 0; kk < 32; ++kk) {
            float4 w4 = Ws[(kt * 32 + kk) * 4 + cg];
            #pragma unroll
            for (int m = 0; m < 4; ++m) {
                float xv = Xs[kk][q + 64 * m];
                acc[m].x += xv * w4.x;
                acc[m].y += xv * w4.y;
                acc[m].z += xv * w4.z;
                acc[m].w += xv * w4.w;
            }
        }
    }
    #pragma unroll
    for (int m = 0; m < 4; ++m) {
        int r = rowbase + q + 64 * m;
        if (r < NN) {
            float dv = dinv[r];
            acc[m].x *= dv; acc[m].y *= dv; acc[m].z *= dv; acc[m].w *= dv;
            *(float4*)(h1s + (size_t)r * F1 + cg * 4) = acc[m];
        }
    }
}

// ---------- K4: fused gather-1 + gemm2: h2s = (relu(dinv*(Σ h1s)+b1) @ W2)*dinv ----------
// One node per wave; 4 lane-groups of 16; 8 neighbor rows in flight per group.
__global__ __launch_bounds__(256) void k_gathm(const unsigned* __restrict__ cursor,
                                               const int* __restrict__ ecol,
                                               const float* __restrict__ dinv,
                                               const float* __restrict__ b1,
                                               const float* __restrict__ W2,
                                               const float* __restrict__ h1s,
                                               float* __restrict__ h2s) {
    __shared__ float Ws[512];   // W2 [16][32]
    __shared__ float B1[16];
    int tid = threadIdx.x;
    Ws[tid] = W2[tid];
    Ws[tid + 256] = W2[tid + 256];
    if (tid < 16) B1[tid] = b1[tid];
    __syncthreads();
    int node = blockIdx.x * 4 + (tid >> 6);
    if (node >= NN) return;
    int lane = tid & 63;
    int f = lane & 15, nb = lane >> 4;            // 4 neighbor groups, stride 4
    unsigned s = node ? cursor[node - 1] : 0u;
    unsigned e = cursor[node];
    float acc = (nb == 0) ? h1s[(size_t)node * F1 + f] : 0.f;
    unsigned j = s + nb;
    while (j + 28 < e) {        // 8 rows in flight
        int c0 = ecol[j],      c1 = ecol[j + 4],  c2 = ecol[j + 8],  c3 = ecol[j + 12];
        int c4 = ecol[j + 16], c5 = ecol[j + 20], c6 = ecol[j + 24], c7 = ecol[j + 28];
        float a0 = h1s[(size_t)c0 * F1 + f], a1 = h1s[(size_t)c1 * F1 + f];
        float a2 = h1s[(size_t)c2 * F1 + f], a3 = h1s[(size_t)c3 * F1 + f];
        float a4 = h1s[(size_t)c4 * F1 + f], a5 = h1s[(size_t)c5 * F1 + f];
        float a6 = h1s[(size_t)c6 * F1 + f], a7 = h1s[(size_t)c7 * F1 + f];
        acc += ((a0 + a1) + (a2 + a3)) + ((a4 + a5) + (a6 + a7));
        j += 32;
    }
    for (; j < e; j += 4) acc += h1s[(size_t)ecol[j] * F1 + f];
    acc += __shfl_xor(acc, 16);
    acc += __shfl_xor(acc, 32);
    float dv = dinv[node];
    float r = fmaxf(acc * dv + B1[f], 0.f);
    float rv[16];
    #pragma unroll
    for (int q = 0; q < 16; ++q) rv[q] = __shfl(r, q);
    if (lane < 32) {
        float a = 0.f;
        #pragma unroll
        for (int q = 0; q < 16; ++q) a += rv[q] * Ws[q * 32 + lane];
        h2s[(size_t)node * F2 + lane] = a * dv;
    }
}

// ---------- K6: gather layer 2 — one node per wave, 16 rows in flight ----------
__global__ __launch_bounds__(256) void k_gath2(const unsigned* __restrict__ cursor,
                                               const int* __restrict__ ecol,
                                               const float* __restrict__ dinv,
                                               const float* __restrict__ b2,
                                               const float* __restrict__ h2s,
                                               float* __restrict__ out2) {
    int tid = threadIdx.x;
    int node = blockIdx.x * 4 + (tid >> 6);
    if (node >= NN) return;
    int lane = tid & 63;
    int f = lane & 31, nb = lane >> 5;            // 2 neighbor groups, stride 2
    unsigned s = node ? cursor[node - 1] : 0u;
    unsigned e = cursor[node];
    float acc = (nb == 0) ? h2s[(size_t)node * F2 + f] : 0.f;
    unsigned j = s + nb;
    while (j + 14 < e) {        // 8 rows in flight per group
        int c0 = ecol[j],      c1 = ecol[j + 2],  c2 = ecol[j + 4],  c3 = ecol[j + 6];
        int c4 = ecol[j + 8],  c5 = ecol[j + 10], c6 = ecol[j + 12], c7 = ecol[j + 14];
        float a0 = h2s[(size_t)c0 * F2 + f], a1 = h2s[(size_t)c1 * F2 + f];
        float a2 = h2s[(size_t)c2 * F2 + f], a3 = h2s[(size_t)c3 * F2 + f];
        float a4 = h2s[(size_t)c4 * F2 + f], a5 = h2s[(size_t)c5 * F2 + f];
        float a6 = h2s[(size_t)c6 * F2 + f], a7 = h2s[(size_t)c7 * F2 + f];
        acc += ((a0 + a1) + (a2 + a3)) + ((a4 + a5) + (a6 + a7));
        j += 16;
    }
    for (; j < e; j += 2) acc += h2s[(size_t)ecol[j] * F2 + f];
    acc += __shfl_xor(acc, 32);
    if (lane < 32) out2[(size_t)node * F2 + f] = acc * dinv[node] + b2[f];
}

// ---------- K7: conv1d(32->64, k=3, pad 1) + global max ----------
#define NPB 256
__global__ __launch_bounds__(256) void k_conv(const float* __restrict__ h2f,
                                              const float* __restrict__ cw,
                                              unsigned* __restrict__ pool) {
    __shared__ float Hs[NPB + 2][33];
    __shared__ float Wt[3 * 32 * 64];
    __shared__ float4 Ms[4][16];
    int tid = threadIdx.x;
    int base = blockIdx.x * NPB;
    for (int idx = tid; idx < 6144; idx += 256) {
        int o = idx / 96, r = idx % 96, ci = r / 3, k = r % 3;
        Wt[(k * 32 + ci) * 64 + o] = cw[idx];
    }
    for (int idx = tid; idx < (NPB + 2) * 8; idx += 256) {
        int j = idx >> 3, c4 = (idx & 7) << 2;
        int g = base + j - 1;
        float4 v = make_float4(0.f, 0.f, 0.f, 0.f);
        if (g >= 0 && g < NN) v = *(const float4*)(h2f + (size_t)g * F2 + c4);
        Hs[j][c4 + 0] = v.x;
        Hs[j][c4 + 1] = v.y;
        Hs[j][c4 + 2] = v.z;
        Hs[j][c4 + 3] = v.w;
    }
    __syncthreads();

    int o4 = (tid & 15) * 4;
    int ng = tid >> 4;
    float4 acc[16] = {};
    for (int ci = 0; ci < 32; ++ci) {
        float h[18];
        #pragma unroll
        for (int j = 0; j < 18; ++j) h[j] = Hs[ng * 16 + j][ci];
        #pragma unroll
        for (int k = 0; k < 3; ++k) {
            float4 w = *(const float4*)&Wt[(k * 32 + ci) * 64 + o4];
            #pragma unroll
            for (int i = 0; i < 16; ++i) {
                float hv = h[i + k];
                acc[i].x += hv * w.x;
                acc[i].y += hv * w.y;
                acc[i].z += hv * w.z;
                acc[i].w += hv * w.w;
            }
        }
    }
    const float NI = -3.0e38f;
    float4 m4 = make_float4(NI, NI, NI, NI);
    #pragma unroll
    for (int i = 0; i < 16; ++i) {
        if (base + ng * 16 + i < NN) {
            m4.x = fmaxf(m4.x, acc[i].x);
            m4.y = fmaxf(m4.y, acc[i].y);
            m4.z = fmaxf(m4.z, acc[i].z);
            m4.w = fmaxf(m4.w, acc[i].w);
        }
    }
    #pragma unroll
    for (int off = 16; off <= 32; off <<= 1) {
        m4.x = fmaxf(m4.x, __shfl_xor(m4.x, off));
        m4.y = fmaxf(m4.y, __shfl_xor(m4.y, off));
        m4.z = fmaxf(m4.z, __shfl_xor(m4.z, off));
        m4.w = fmaxf(m4.w, __shfl_xor(m4.w, off));
    }
    int lane = tid & 63, wv = tid >> 6;
    if (lane < 16) Ms[wv][lane] = m4;
    __syncthreads();
    if (tid < 16) {
        float4 a = Ms[0][tid], b = Ms[1][tid], c = Ms[2][tid], d = Ms[3][tid];
        a.x = fmaxf(fmaxf(a.x, b.x), fmaxf(c.x, d.x));
        a.y = fmaxf(fmaxf(a.y, b.y), fmaxf(c.y, d.y));
        a.z = fmaxf(fmaxf(a.z, b.z), fmaxf(c.z, d.z));
        a.w = fmaxf(fmaxf(a.w, b.w), fmaxf(c.w, d.w));
        int o = tid * 4;
        atomicMax(&pool[o + 0], enc_f(a.x));
        atomicMax(&pool[o + 1], enc_f(a.y));
        atomicMax(&pool[o + 2], enc_f(a.z));
        atomicMax(&pool[o + 3], enc_f(a.w));
    }
}

// ---------- K8: out = (pooled + conv_b) @ fc_w^T + fc_b ----------
__global__ void k_fc(const unsigned* __restrict__ pool, const float* __restrict__ cb,
                     const float* __restrict__ fw, const float* __restrict__ fb,
                     float* __restrict__ out) {
    __shared__ float P[64];
    int tid = threadIdx.x;
    if (tid < 64) P[tid] = dec_f(pool[tid]) + cb[tid];
    __syncthreads();
    int j = blockIdx.x * 256 + tid;
    if (j >= NC) return;
    float s = fb[j];
    const float4* wr = (const float4*)(fw + (size_t)j * CO);
    #pragma unroll
    for (int c = 0; c < 16; ++c) {
        float4 w = wr[c];
        s += P[c * 4 + 0] * w.x + P[c * 4 + 1] * w.y +
             P[c * 4 + 2] * w.z + P[c * 4 + 3] * w.w;
    }
    out[j] = s;
}

extern "C" void kernel_launch(void* const* d_in, const int* in_sizes, int n_in,
                              void* d_out, int out_size, void* d_ws, size_t ws_size,
                              hipStream_t stream) {
    const float* x  = (const float*)d_in[0];
    const int*   ei = (const int*)d_in[1];
    const float* W1 = (const float*)d_in[2];
    const float* b1 = (const float*)d_in[3];
    const float* W2 = (const float*)d_in[4];
    const float* b2 = (const float*)d_in[5];
    const float* cw = (const float*)d_in[6];
    const float* cb = (const float*)d_in[7];
    const float* fw = (const float*)d_in[8];
    const float* fb = (const float*)d_in[9];

    float* ws = (float*)d_ws;
    float*    dinv   = ws + OFF_DINV;
    unsigned* cursor = (unsigned*)(ws + OFF_CUR);
    unsigned* deg    = (unsigned*)(ws + OFF_DEG);
    int*      ecol   = (int*)(ws + OFF_ECOL);
    unsigned* pcnt   = (unsigned*)(ws + OFF_MISC);
    unsigned* pbase  = pcnt + 8;
    unsigned* pcur   = pcnt + 16;
    unsigned* pool   = pcnt + 64;
    unsigned* bsum   = pcnt + 512;
    int*      dpart  = (int*)(ws + OFF_DPART);
    int*      spart  = (int*)(ws + OFF_SPART);
    unsigned* hist   = (unsigned*)(ws + OFF_HIST);
    float*    h1s    = ws + OFF_H1S;
    float*    h2s    = ws + OFF_H2S;
    float*    out2   = ws + OFF_OUT2;

    hipMemsetAsync(pcnt, 0, 8 * 4, stream);
    hipMemsetAsync(pool, 0, 64 * 4, stream);

    k_pcount <<<NE / (256 * BK), 256, 0, stream>>>(ei, pcnt);          // 625 blocks
    k_pscan  <<<1, 64, 0, stream>>>(pcnt, pbase, pcur);
    k_bucket <<<NE / (256 * BK), 256, 0, stream>>>(ei, pcur, dpart, spart);
    k_hist   <<<CH * NPART, 256, 0, stream>>>(pbase, pcnt, dpart, hist);   // 128 blocks
    k_colscan<<<NBLK, 256, 0, stream>>>(hist, deg);
    k_bsum   <<<NBLK, 256, 0, stream>>>(deg, bsum);
    k_bscan  <<<1, 512, 0, stream>>>(bsum);
    k_cscan  <<<NBLK, 256, 0, stream>>>(deg, bsum, cursor, dinv);
    k_place  <<<CH * NPART, 256, 0, stream>>>(pbase, pcnt, dpart, spart, hist, cursor, ecol);
    k_gemm1  <<<NBLK, 256, 0, stream>>>(x, W1, dinv, h1s);
    k_gathm  <<<(NN + 3) / 4, 256, 0, stream>>>(cursor, ecol, dinv, b1, W2, h1s, h2s);
    k_gath2  <<<(NN + 3) / 4, 256, 0, stream>>>(cursor, ecol, dinv, b2, h2s, out2);
    k_conv   <<<(NN + NPB - 1) / NPB, 256, 0, stream>>>(out2, cw, pool);
    k_fc     <<<4, 256, 0, stream>>>(pool, cb, fw, fb, (float*)d_out);
}

// Round 9
// 392.369 us; speedup vs baseline: 1.0889x; 1.0889x over previous
//
#include <hip/hip_runtime.h>
#include <hip/hip_bf16.h>
#include <hip/hip_fp16.h>

#define NN 100000
#define NE 3200000
#define FIN 256
#define F1 16
#define F2 32
#define CO 64
#define NC 1000
#define NBLK 391   /* ceil(NN/256) */
#define NPART 8
#define PSZ 12500  /* NN / NPART */
#define BK 20      /* edges per thread in pcount/bucket; 625 blocks * 256 * 20 = NE */
#define CH 16      /* chunks per partition for hist/place */

// workspace layout (float offsets) — total 11,502,080 floats = 46.0 MB
#define OFF_DINV 0
#define OFF_CUR  100352
#define OFF_DEG  200704
#define OFF_ECOL 301056
#define OFF_MISC 3501056   /* pcnt[8], pbase[8], pcur[8], pool[64]@64, bsum[512]@512 */
#define OFF_DPART 3502080
#define OFF_SPART 6702080
#define OFF_HIST 9902080   /* u32[NPART*CH*PSZ] = 1.6M */
#define OFF_H1S  3502080   /* fp16, 800K floats; overlays dpart (dead after place) */
#define OFF_H2S  6702080   /* fp16, 1.6M floats (ends 8302080); overlays spart (dead after place) */
#define OFF_OUT2 3502080   /* f32 3.2M floats: 3502080..6702080 — overlays h1h+dpart (dead
                              after gathm), ends exactly at h2h start. MUST NOT cross 6702080. */

__device__ __forceinline__ unsigned enc_f(float f) {
    unsigned u = __float_as_uint(f);
    return (u & 0x80000000u) ? ~u : (u | 0x80000000u);
}
__device__ __forceinline__ float dec_f(unsigned u) {
    return (u & 0x80000000u) ? __uint_as_float(u & 0x7fffffffu) : __uint_as_float(~u);
}

// ---------- K0a: partition edge counts (ballot-based, no LDS) ----------
__global__ __launch_bounds__(256) void k_pcount(const int* __restrict__ ei,
                                                unsigned* __restrict__ pcnt) {
    int t = threadIdx.x, lane = t & 63;
    int base = blockIdx.x * (256 * BK) + t;
    unsigned cnt = 0;
    #pragma unroll
    for (int k = 0; k < BK; ++k) {
        int bin = (unsigned)ei[NE + base + k * 256] / PSZ;
        #pragma unroll
        for (int b = 0; b < 8; ++b) {
            unsigned long long m = __ballot(bin == b);
            if (lane == b) cnt += (unsigned)__popcll(m);
        }
    }
    if (lane < 8) atomicAdd(&pcnt[lane], cnt);
}

// ---------- K0b: 8-way exclusive prefix -> pbase, pcur ----------
__global__ void k_pscan(const unsigned* __restrict__ pcnt, unsigned* __restrict__ pbase,
                        unsigned* __restrict__ pcur) {
    int t = threadIdx.x;
    if (t < 8) {
        unsigned v = 0;
        for (int i = 0; i < t; ++i) v += pcnt[i];
        pbase[t] = v;
        pcur[t] = v;
    }
}

// ---------- K0c: bucket edges into partition-segmented (dst,src) arrays ----------
__global__ __launch_bounds__(256) void k_bucket(const int* __restrict__ ei,
                                                unsigned* __restrict__ pcur,
                                                int* __restrict__ dpart,
                                                int* __restrict__ spart) {
    int t = threadIdx.x, lane = t & 63;
    int base = blockIdx.x * (256 * BK) + t;
    int dst[BK], src[BK];
    #pragma unroll
    for (int k = 0; k < BK; ++k) {
        dst[k] = ei[NE + base + k * 256];
        src[k] = ei[base + k * 256];
    }
    unsigned long long lt = (lane == 63) ? 0x7fffffffffffffffull
                                         : ((1ull << lane) - 1ull);
    unsigned cnt = 0;
    #pragma unroll
    for (int k = 0; k < BK; ++k) {
        int bin = (unsigned)dst[k] / PSZ;
        #pragma unroll
        for (int b = 0; b < 8; ++b) {
            unsigned long long m = __ballot(bin == b);
            if (lane == b) cnt += (unsigned)__popcll(m);
        }
    }
    unsigned run = 0;
    if (lane < 8) run = atomicAdd(&pcur[lane], cnt);
    #pragma unroll
    for (int k = 0; k < BK; ++k) {
        int bin = (unsigned)dst[k] / PSZ;
        unsigned long long mym = 0;
        unsigned myrun = 0;
        #pragma unroll
        for (int b = 0; b < 8; ++b) {
            unsigned long long m = __ballot(bin == b);
            unsigned r = __shfl(run, b);
            if (bin == b) { mym = m; myrun = r; }
            if (lane == b) run += (unsigned)__popcll(m);
        }
        unsigned pos = myrun + (unsigned)__popcll(mym & lt);
        dpart[pos] = dst[k];
        spart[pos] = src[k];
    }
}

// ---------- K0d: per-chunk LDS histograms -> hist[p][c][i] ----------
__global__ __launch_bounds__(256) void k_hist(const unsigned* __restrict__ pbase,
                                              const unsigned* __restrict__ pcnt,
                                              const int* __restrict__ dpart,
                                              unsigned* __restrict__ hist) {
    __shared__ unsigned lh[PSZ];
    int p = blockIdx.x & 7;
    int c = blockIdx.x >> 3;               // 0..CH-1
    int t = threadIdx.x;
    for (int i = t; i < PSZ; i += 256) lh[i] = 0;
    __syncthreads();
    unsigned s = pbase[p], n = pcnt[p];
    unsigned c0 = s + (unsigned)(((unsigned long long)n * c) / CH);
    unsigned c1 = s + (unsigned)(((unsigned long long)n * (c + 1)) / CH);
    int pb = p * PSZ;
    for (unsigned j = c0 + t; j < c1; j += 256)
        atomicAdd(&lh[dpart[j] - pb], 1u);
    __syncthreads();
    unsigned* hrow = hist + (unsigned)(p * CH + c) * PSZ;
    for (int i = t; i < PSZ; i += 256) hrow[i] = lh[i];
}

// ---------- K0e: scan chunk counts per bin -> chunk bases (in place) + deg ----------
__global__ __launch_bounds__(256) void k_colscan(unsigned* __restrict__ hist,
                                                 unsigned* __restrict__ deg) {
    int gid = blockIdx.x * 256 + threadIdx.x;
    if (gid >= NN) return;
    int p = gid / PSZ, i = gid % PSZ;
    unsigned run = 0;
    #pragma unroll
    for (int c = 0; c < CH; ++c) {
        unsigned idx = (unsigned)(p * CH + c) * PSZ + i;
        unsigned v = hist[idx];
        hist[idx] = run;
        run += v;
    }
    deg[gid] = run;
}

// ---------- K1a: per-block degree sums ----------
__global__ void k_bsum(const unsigned* __restrict__ deg, unsigned* __restrict__ bsum) {
    __shared__ unsigned W[4];
    int t = threadIdx.x;
    int i = blockIdx.x * 256 + t;
    unsigned d = (i < NN) ? deg[i] : 0u;
    #pragma unroll
    for (int off = 1; off < 64; off <<= 1) d += __shfl_xor(d, off);
    if ((t & 63) == 0) W[t >> 6] = d;
    __syncthreads();
    if (t == 0) bsum[blockIdx.x] = W[0] + W[1] + W[2] + W[3];
}

// ---------- K1b: exclusive scan of block sums (1 block) ----------
__global__ __launch_bounds__(512) void k_bscan(unsigned* __restrict__ bsum) {
    __shared__ unsigned S[512];
    int t = threadIdx.x;
    unsigned v = (t < NBLK) ? bsum[t] : 0u;
    S[t] = v;
    __syncthreads();
    for (int off = 1; off < 512; off <<= 1) {
        unsigned u = (t >= off) ? S[t - off] : 0u;
        __syncthreads();
        S[t] += u;
        __syncthreads();
    }
    if (t < NBLK) bsum[t] = S[t] - v;   // exclusive prefix
}

// ---------- K1c: per-block scan -> cursor[i] = rowptr[i+1] (inclusive), dinv ----------
__global__ void k_cscan(const unsigned* __restrict__ deg, const unsigned* __restrict__ bsum,
                        unsigned* __restrict__ cursor, float* __restrict__ dinv) {
    __shared__ unsigned S[256];
    int t = threadIdx.x;
    int i = blockIdx.x * 256 + t;
    unsigned d = (i < NN) ? deg[i] : 0u;
    S[t] = d;
    __syncthreads();
    for (int off = 1; off < 256; off <<= 1) {
        unsigned u = (t >= off) ? S[t - off] : 0u;
        __syncthreads();
        S[t] += u;
        __syncthreads();
    }
    if (i < NN) {
        cursor[i] = bsum[blockIdx.x] + S[t];       // inclusive = rowptr[i+1]
        dinv[i] = rsqrtf((float)(d + 1u));
    }
}

// ---------- K2: place edges via LDS cursors (no global atomics) ----------
__global__ __launch_bounds__(256) void k_place(const unsigned* __restrict__ pbase,
                                               const unsigned* __restrict__ pcnt,
                                               const int* __restrict__ dpart,
                                               const int* __restrict__ spart,
                                               const unsigned* __restrict__ hist,
                                               const unsigned* __restrict__ cursor,
                                               int* __restrict__ ecol) {
    __shared__ unsigned lcur[PSZ];
    int p = blockIdx.x & 7;
    int c = blockIdx.x >> 3;
    int t = threadIdx.x;
    int pb = p * PSZ;
    const unsigned* hrow = hist + (unsigned)(p * CH + c) * PSZ;
    for (int i = t; i < PSZ; i += 256) {
        int gi = pb + i;
        unsigned rowstart = gi ? cursor[gi - 1] : 0u;
        lcur[i] = rowstart + hrow[i];
    }
    __syncthreads();
    unsigned s = pbase[p], n = pcnt[p];
    unsigned c0 = s + (unsigned)(((unsigned long long)n * c) / CH);
    unsigned c1 = s + (unsigned)(((unsigned long long)n * (c + 1)) / CH);
    for (unsigned j = c0 + t; j < c1; j += 256) {
        int dst = dpart[j];
        int src = spart[j];
        unsigned pos = atomicAdd(&lcur[dst - pb], 1u);
        ecol[pos] = src;
    }
}

// ---------- K3: h1h = fp16((X @ W1) * dinv[row]) ----------
__global__ __launch_bounds__(256) void k_gemm1(const float* __restrict__ X,
                                               const float* __restrict__ W1,
                                               const float* __restrict__ dinv,
                                               __half2* __restrict__ h1h) {
    __shared__ float Xs[32][257];
    __shared__ float4 Ws[1024];
    int tid = threadIdx.x;
    const float4* W14 = (const float4*)W1;
    for (int i = tid; i < 1024; i += 256) Ws[i] = W14[i];

    int rowbase = blockIdx.x * 256;
    int q  = tid >> 2;
    int cg = tid & 3;
    float4 acc[4] = {};

    for (int kt = 0; kt < 8; ++kt) {
        __syncthreads();
        #pragma unroll
        for (int it = 0; it < 8; ++it) {
            int fl = tid + it * 256;
            int rl = fl >> 3;
            int c4 = (fl & 7) << 2;
            int gr = rowbase + rl;
            float4 v = make_float4(0.f, 0.f, 0.f, 0.f);
            if (gr < NN) v = *(const float4*)(X + (size_t)gr * FIN + kt * 32 + c4);
            Xs[c4 + 0][rl] = v.x;
            Xs[c4 + 1][rl] = v.y;
            Xs[c4 + 2][rl] = v.z;
            Xs[c4 + 3][rl] = v.w;
        }
        __syncthreads();
        #pragma unroll
        for (int kk = 0; kk < 32; ++kk) {
            float4 w4 = Ws[(kt * 32 + kk) * 4 + cg];
            #pragma unroll
            for (int m = 0; m < 4; ++m) {
                float xv = Xs[kk][q + 64 * m];
                acc[m].x += xv * w4.x;
                acc[m].y += xv * w4.y;
                acc[m].z += xv * w4.z;
                acc[m].w += xv * w4.w;
            }
        }
    }
    #pragma unroll
    for (int m = 0; m < 4; ++m) {
        int r = rowbase + q + 64 * m;
        if (r < NN) {
            float dv = dinv[r];
            union { __half2 h[2]; uint2 u; } pk;
            pk.h[0] = __floats2half2_rn(acc[m].x * dv, acc[m].y * dv);
            pk.h[1] = __floats2half2_rn(acc[m].z * dv, acc[m].w * dv);
            *(uint2*)(h1h + (size_t)r * 8 + cg * 2) = pk.u;
        }
    }
}

// ---------- K4: fused gather-1 + gemm2 (fp16 in/out, f32 accumulate) ----------
// One node per wave; 8 lane-groups of 8; lane handles a half2 (2 features).
__global__ __launch_bounds__(256) void k_gathm(const unsigned* __restrict__ cursor,
                                               const int* __restrict__ ecol,
                                               const float* __restrict__ dinv,
                                               const float* __restrict__ b1,
                                               const float* __restrict__ W2,
                                               const __half2* __restrict__ h1h,
                                               __half2* __restrict__ h2h) {
    __shared__ float Ws[512];   // W2 [16][32]
    __shared__ float B1[16];
    int tid = threadIdx.x;
    Ws[tid] = W2[tid];
    Ws[tid + 256] = W2[tid + 256];
    if (tid < 16) B1[tid] = b1[tid];
    __syncthreads();
    int node = blockIdx.x * 4 + (tid >> 6);
    if (node >= NN) return;
    int lane = tid & 63;
    int f2 = lane & 7, nb = lane >> 3;            // 8 neighbor groups, stride 8
    unsigned s = node ? cursor[node - 1] : 0u;
    unsigned e = cursor[node];
    float2 acc = make_float2(0.f, 0.f);
    if (nb == 0) acc = __half22float2(h1h[(size_t)node * 8 + f2]);
    unsigned j = s + nb;
    while (j + 24 < e) {        // 4 rows in flight per group (32/wave)
        int c0 = ecol[j], c1 = ecol[j + 8], c2 = ecol[j + 16], c3 = ecol[j + 24];
        float2 a0 = __half22float2(h1h[(size_t)c0 * 8 + f2]);
        float2 a1 = __half22float2(h1h[(size_t)c1 * 8 + f2]);
        float2 a2 = __half22float2(h1h[(size_t)c2 * 8 + f2]);
        float2 a3 = __half22float2(h1h[(size_t)c3 * 8 + f2]);
        acc.x += (a0.x + a1.x) + (a2.x + a3.x);
        acc.y += (a0.y + a1.y) + (a2.y + a3.y);
        j += 32;
    }
    for (; j < e; j += 8) {
        float2 a = __half22float2(h1h[(size_t)ecol[j] * 8 + f2]);
        acc.x += a.x; acc.y += a.y;
    }
    acc.x += __shfl_xor(acc.x, 8);  acc.y += __shfl_xor(acc.y, 8);
    acc.x += __shfl_xor(acc.x, 16); acc.y += __shfl_xor(acc.y, 16);
    acc.x += __shfl_xor(acc.x, 32); acc.y += __shfl_xor(acc.y, 32);
    float dv = dinv[node];
    float r0 = fmaxf(acc.x * dv + B1[2 * f2], 0.f);
    float r1 = fmaxf(acc.y * dv + B1[2 * f2 + 1], 0.f);
    float rv[16];
    #pragma unroll
    for (int q = 0; q < 8; ++q) {
        rv[2 * q]     = __shfl(r0, q);
        rv[2 * q + 1] = __shfl(r1, q);
    }
    if (lane < 16) {
        float a0 = 0.f, a1 = 0.f;
        #pragma unroll
        for (int q = 0; q < 16; ++q) {
            a0 += rv[q] * Ws[q * 32 + 2 * lane];
            a1 += rv[q] * Ws[q * 32 + 2 * lane + 1];
        }
        h2h[(size_t)node * 16 + lane] = __floats2half2_rn(a0 * dv, a1 * dv);
    }
}

// ---------- K6: gather layer 2 (fp16 in, f32 out) ----------
// One node per wave; 4 lane-groups of 16; lane handles a half2.
__global__ __launch_bounds__(256) void k_gath2(const unsigned* __restrict__ cursor,
                                               const int* __restrict__ ecol,
                                               const float* __restrict__ dinv,
                                               const float* __restrict__ b2,
                                               const __half2* __restrict__ h2h,
                                               float* __restrict__ out2) {
    int tid = threadIdx.x;
    int node = blockIdx.x * 4 + (tid >> 6);
    if (node >= NN) return;
    int lane = tid & 63;
    int f2 = lane & 15, nb = lane >> 4;           // 4 neighbor groups, stride 4
    unsigned s = node ? cursor[node - 1] : 0u;
    unsigned e = cursor[node];
    float2 acc = make_float2(0.f, 0.f);
    if (nb == 0) acc = __half22float2(h2h[(size_t)node * 16 + f2]);
    unsigned j = s + nb;
    while (j + 12 < e) {        // 4 rows in flight per group (16/wave)
        int c0 = ecol[j], c1 = ecol[j + 4], c2 = ecol[j + 8], c3 = ecol[j + 12];
        float2 a0 = __half22float2(h2h[(size_t)c0 * 16 + f2]);
        float2 a1 = __half22float2(h2h[(size_t)c1 * 16 + f2]);
        float2 a2 = __half22float2(h2h[(size_t)c2 * 16 + f2]);
        float2 a3 = __half22float2(h2h[(size_t)c3 * 16 + f2]);
        acc.x += (a0.x + a1.x) + (a2.x + a3.x);
        acc.y += (a0.y + a1.y) + (a2.y + a3.y);
        j += 16;
    }
    for (; j < e; j += 4) {
        float2 a = __half22float2(h2h[(size_t)ecol[j] * 16 + f2]);
        acc.x += a.x; acc.y += a.y;
    }
    acc.x += __shfl_xor(acc.x, 16); acc.y += __shfl_xor(acc.y, 16);
    acc.x += __shfl_xor(acc.x, 32); acc.y += __shfl_xor(acc.y, 32);
    if (lane < 16) {
        float dv = dinv[node];
        float2 b = ((const float2*)b2)[f2];
        ((float2*)(out2 + (size_t)node * F2))[f2] =
            make_float2(acc.x * dv + b.x, acc.y * dv + b.y);
    }
}

// ---------- K7: conv1d(32->64, k=3, pad 1) + global max ----------
#define NPB 256
__global__ __launch_bounds__(256) void k_conv(const float* __restrict__ h2f,
                                              const float* __restrict__ cw,
                                              unsigned* __restrict__ pool) {
    __shared__ float Hs[NPB + 2][33];
    __shared__ float Wt[3 * 32 * 64];
    __shared__ float4 Ms[4][16];
    int tid = threadIdx.x;
    int base = blockIdx.x * NPB;
    for (int idx = tid; idx < 6144; idx += 256) {
        int o = idx / 96, r = idx % 96, ci = r / 3, k = r % 3;
        Wt[(k * 32 + ci) * 64 + o] = cw[idx];
    }
    for (int idx = tid; idx < (NPB + 2) * 8; idx += 256) {
        int j = idx >> 3, c4 = (idx & 7) << 2;
        int g = base + j - 1;
        float4 v = make_float4(0.f, 0.f, 0.f, 0.f);
        if (g >= 0 && g < NN) v = *(const float4*)(h2f + (size_t)g * F2 + c4);
        Hs[j][c4 + 0] = v.x;
        Hs[j][c4 + 1] = v.y;
        Hs[j][c4 + 2] = v.z;
        Hs[j][c4 + 3] = v.w;
    }
    __syncthreads();

    int o4 = (tid & 15) * 4;
    int ng = tid >> 4;
    float4 acc[16] = {};
    for (int ci = 0; ci < 32; ++ci) {
        float h[18];
        #pragma unroll
        for (int j = 0; j < 18; ++j) h[j] = Hs[ng * 16 + j][ci];
        #pragma unroll
        for (int k = 0; k < 3; ++k) {
            float4 w = *(const float4*)&Wt[(k * 32 + ci) * 64 + o4];
            #pragma unroll
            for (int i = 0; i < 16; ++i) {
                float hv = h[i + k];
                acc[i].x += hv * w.x;
                acc[i].y += hv * w.y;
                acc[i].z += hv * w.z;
                acc[i].w += hv * w.w;
            }
        }
    }
    const float NI = -3.0e38f;
    float4 m4 = make_float4(NI, NI, NI, NI);
    #pragma unroll
    for (int i = 0; i < 16; ++i) {
        if (base + ng * 16 + i < NN) {
            m4.x = fmaxf(m4.x, acc[i].x);
            m4.y = fmaxf(m4.y, acc[i].y);
            m4.z = fmaxf(m4.z, acc[i].z);
            m4.w = fmaxf(m4.w, acc[i].w);
        }
    }
    #pragma unroll
    for (int off = 16; off <= 32; off <<= 1) {
        m4.x = fmaxf(m4.x, __shfl_xor(m4.x, off));
        m4.y = fmaxf(m4.y, __shfl_xor(m4.y, off));
        m4.z = fmaxf(m4.z, __shfl_xor(m4.z, off));
        m4.w = fmaxf(m4.w, __shfl_xor(m4.w, off));
    }
    int lane = tid & 63, wv = tid >> 6;
    if (lane < 16) Ms[wv][lane] = m4;
    __syncthreads();
    if (tid < 16) {
        float4 a = Ms[0][tid], b = Ms[1][tid], c = Ms[2][tid], d = Ms[3][tid];
        a.x = fmaxf(fmaxf(a.x, b.x), fmaxf(c.x, d.x));
        a.y = fmaxf(fmaxf(a.y, b.y), fmaxf(c.y, d.y));
        a.z = fmaxf(fmaxf(a.z, b.z), fmaxf(c.z, d.z));
        a.w = fmaxf(fmaxf(a.w, b.w), fmaxf(c.w, d.w));
        int o = tid * 4;
        atomicMax(&pool[o + 0], enc_f(a.x));
        atomicMax(&pool[o + 1], enc_f(a.y));
        atomicMax(&pool[o + 2], enc_f(a.z));
        atomicMax(&pool[o + 3], enc_f(a.w));
    }
}

// ---------- K8: out = (pooled + conv_b) @ fc_w^T + fc_b ----------
__global__ void k_fc(const unsigned* __restrict__ pool, const float* __restrict__ cb,
                     const float* __restrict__ fw, const float* __restrict__ fb,
                     float* __restrict__ out) {
    __shared__ float P[64];
    int tid = threadIdx.x;
    if (tid < 64) P[tid] = dec_f(pool[tid]) + cb[tid];
    __syncthreads();
    int j = blockIdx.x * 256 + tid;
    if (j >= NC) return;
    float s = fb[j];
    const float4* wr = (const float4*)(fw + (size_t)j * CO);
    #pragma unroll
    for (int c = 0; c < 16; ++c) {
        float4 w = wr[c];
        s += P[c * 4 + 0] * w.x + P[c * 4 + 1] * w.y +
             P[c * 4 + 2] * w.z + P[c * 4 + 3] * w.w;
    }
    out[j] = s;
}

extern "C" void kernel_launch(void* const* d_in, const int* in_sizes, int n_in,
                              void* d_out, int out_size, void* d_ws, size_t ws_size,
                              hipStream_t stream) {
    const float* x  = (const float*)d_in[0];
    const int*   ei = (const int*)d_in[1];
    const float* W1 = (const float*)d_in[2];
    const float* b1 = (const float*)d_in[3];
    const float* W2 = (const float*)d_in[4];
    const float* b2 = (const float*)d_in[5];
    const float* cw = (const float*)d_in[6];
    const float* cb = (const float*)d_in[7];
    const float* fw = (const float*)d_in[8];
    const float* fb = (const float*)d_in[9];

    float* ws = (float*)d_ws;
    float*    dinv   = ws + OFF_DINV;
    unsigned* cursor = (unsigned*)(ws + OFF_CUR);
    unsigned* deg    = (unsigned*)(ws + OFF_DEG);
    int*      ecol   = (int*)(ws + OFF_ECOL);
    unsigned* pcnt   = (unsigned*)(ws + OFF_MISC);
    unsigned* pbase  = pcnt + 8;
    unsigned* pcur   = pcnt + 16;
    unsigned* pool   = pcnt + 64;
    unsigned* bsum   = pcnt + 512;
    int*      dpart  = (int*)(ws + OFF_DPART);
    int*      spart  = (int*)(ws + OFF_SPART);
    unsigned* hist   = (unsigned*)(ws + OFF_HIST);
    __half2*  h1h    = (__half2*)(ws + OFF_H1S);
    __half2*  h2h    = (__half2*)(ws + OFF_H2S);
    float*    out2   = ws + OFF_OUT2;

    hipMemsetAsync(pcnt, 0, 8 * 4, stream);
    hipMemsetAsync(pool, 0, 64 * 4, stream);

    k_pcount <<<NE / (256 * BK), 256, 0, stream>>>(ei, pcnt);          // 625 blocks
    k_pscan  <<<1, 64, 0, stream>>>(pcnt, pbase, pcur);
    k_bucket <<<NE / (256 * BK), 256, 0, stream>>>(ei, pcur, dpart, spart);
    k_hist   <<<CH * NPART, 256, 0, stream>>>(pbase, pcnt, dpart, hist);   // 128 blocks
    k_colscan<<<NBLK, 256, 0, stream>>>(hist, deg);
    k_bsum   <<<NBLK, 256, 0, stream>>>(deg, bsum);
    k_bscan  <<<1, 512, 0, stream>>>(bsum);
    k_cscan  <<<NBLK, 256, 0, stream>>>(deg, bsum, cursor, dinv);
    k_place  <<<CH * NPART, 256, 0, stream>>>(pbase, pcnt, dpart, spart, hist, cursor, ecol);
    k_gemm1  <<<NBLK, 256, 0, stream>>>(x, W1, dinv, h1h);
    k_gathm  <<<(NN + 3) / 4, 256, 0, stream>>>(cursor, ecol, dinv, b1, W2, h1h, h2h);
    k_gath2  <<<(NN + 3) / 4, 256, 0, stream>>>(cursor, ecol, dinv, b2, h2h, out2);
    k_conv   <<<(NN + NPB - 1) / NPB, 256, 0, stream>>>(out2, cw, pool);
    k_fc     <<<4, 256, 0, stream>>>(pool, cb, fw, fb, (float*)d_out);
}

// Round 10
// 386.286 us; speedup vs baseline: 1.1061x; 1.0157x over previous
//
#include <hip/hip_runtime.h>
#include <hip/hip_bf16.h>
#include <hip/hip_fp16.h>

#define NN 100000
#define NE 3200000
#define FIN 256
#define F1 16
#define F2 32
#define CO 64
#define NC 1000
#define NBLK 391   /* ceil(NN/256) */
#define GBLK 782   /* ceil(NN/128) gemm1 grid */
#define NPART 8
#define PSZ 12500  /* NN / NPART */
#define BK 20      /* edges per thread in pcount/bucket; 625 blocks * 256 * 20 = NE */
#define CH 16      /* chunks per partition for hist/place */

// workspace layout (float offsets) — total 11,502,080 floats = 46.0 MB
#define OFF_DINV 0
#define OFF_CUR  100352
#define OFF_DEG  200704
#define OFF_ECOL 301056
#define OFF_MISC 3501056   /* pcnt[8], pbase[8], pcur[8], pool[64]@64, bsum[512]@512 */
#define OFF_DPART 3502080
#define OFF_SPART 6702080
#define OFF_HIST 9902080   /* u32[NPART*CH*PSZ] = 1.6M */
#define OFF_H1S  3502080   /* fp16, 800K floats; overlays dpart (dead after place) */
#define OFF_H2S  6702080   /* fp16, 1.6M floats (ends 8302080); overlays spart (dead after place) */
#define OFF_OUT2 3502080   /* f32 3.2M floats: 3502080..6702080 — overlays h1h+dpart (dead
                              after gathm), ends exactly at h2h start. MUST NOT cross 6702080. */

__device__ __forceinline__ unsigned enc_f(float f) {
    unsigned u = __float_as_uint(f);
    return (u & 0x80000000u) ? ~u : (u | 0x80000000u);
}
__device__ __forceinline__ float dec_f(unsigned u) {
    return (u & 0x80000000u) ? __uint_as_float(u & 0x7fffffffu) : __uint_as_float(~u);
}

// ---------- K0a: partition edge counts (ballot-based, no LDS) ----------
__global__ __launch_bounds__(256) void k_pcount(const int* __restrict__ ei,
                                                unsigned* __restrict__ pcnt) {
    int t = threadIdx.x, lane = t & 63;
    int base = blockIdx.x * (256 * BK) + t;
    unsigned cnt = 0;
    #pragma unroll
    for (int k = 0; k < BK; ++k) {
        int bin = (unsigned)ei[NE + base + k * 256] / PSZ;
        #pragma unroll
        for (int b = 0; b < 8; ++b) {
            unsigned long long m = __ballot(bin == b);
            if (lane == b) cnt += (unsigned)__popcll(m);
        }
    }
    if (lane < 8) atomicAdd(&pcnt[lane], cnt);
}

// ---------- K0b: 8-way exclusive prefix -> pbase, pcur ----------
__global__ void k_pscan(const unsigned* __restrict__ pcnt, unsigned* __restrict__ pbase,
                        unsigned* __restrict__ pcur) {
    int t = threadIdx.x;
    if (t < 8) {
        unsigned v = 0;
        for (int i = 0; i < t; ++i) v += pcnt[i];
        pbase[t] = v;
        pcur[t] = v;
    }
}

// ---------- K0c: bucket edges into partition-segmented (dst,src) arrays ----------
__global__ __launch_bounds__(256) void k_bucket(const int* __restrict__ ei,
                                                unsigned* __restrict__ pcur,
                                                int* __restrict__ dpart,
                                                int* __restrict__ spart) {
    int t = threadIdx.x, lane = t & 63;
    int base = blockIdx.x * (256 * BK) + t;
    int dst[BK], src[BK];
    #pragma unroll
    for (int k = 0; k < BK; ++k) {
        dst[k] = ei[NE + base + k * 256];
        src[k] = ei[base + k * 256];
    }
    unsigned long long lt = (lane == 63) ? 0x7fffffffffffffffull
                                         : ((1ull << lane) - 1ull);
    unsigned cnt = 0;
    #pragma unroll
    for (int k = 0; k < BK; ++k) {
        int bin = (unsigned)dst[k] / PSZ;
        #pragma unroll
        for (int b = 0; b < 8; ++b) {
            unsigned long long m = __ballot(bin == b);
            if (lane == b) cnt += (unsigned)__popcll(m);
        }
    }
    unsigned run = 0;
    if (lane < 8) run = atomicAdd(&pcur[lane], cnt);
    #pragma unroll
    for (int k = 0; k < BK; ++k) {
        int bin = (unsigned)dst[k] / PSZ;
        unsigned long long mym = 0;
        unsigned myrun = 0;
        #pragma unroll
        for (int b = 0; b < 8; ++b) {
            unsigned long long m = __ballot(bin == b);
            unsigned r = __shfl(run, b);
            if (bin == b) { mym = m; myrun = r; }
            if (lane == b) run += (unsigned)__popcll(m);
        }
        unsigned pos = myrun + (unsigned)__popcll(mym & lt);
        dpart[pos] = dst[k];
        spart[pos] = src[k];
    }
}

// ---------- K0d: per-chunk LDS histograms -> hist[p][c][i] ----------
__global__ __launch_bounds__(256) void k_hist(const unsigned* __restrict__ pbase,
                                              const unsigned* __restrict__ pcnt,
                                              const int* __restrict__ dpart,
                                              unsigned* __restrict__ hist) {
    __shared__ unsigned lh[PSZ];
    int p = blockIdx.x & 7;
    int c = blockIdx.x >> 3;               // 0..CH-1
    int t = threadIdx.x;
    for (int i = t; i < PSZ; i += 256) lh[i] = 0;
    __syncthreads();
    unsigned s = pbase[p], n = pcnt[p];
    unsigned c0 = s + (unsigned)(((unsigned long long)n * c) / CH);
    unsigned c1 = s + (unsigned)(((unsigned long long)n * (c + 1)) / CH);
    int pb = p * PSZ;
    for (unsigned j = c0 + t; j < c1; j += 256)
        atomicAdd(&lh[dpart[j] - pb], 1u);
    __syncthreads();
    unsigned* hrow = hist + (unsigned)(p * CH + c) * PSZ;
    for (int i = t; i < PSZ; i += 256) hrow[i] = lh[i];
}

// ---------- K0e: scan chunk counts per bin -> chunk bases (in place) + deg ----------
__global__ __launch_bounds__(256) void k_colscan(unsigned* __restrict__ hist,
                                                 unsigned* __restrict__ deg) {
    int gid = blockIdx.x * 256 + threadIdx.x;
    if (gid >= NN) return;
    int p = gid / PSZ, i = gid % PSZ;
    unsigned run = 0;
    #pragma unroll
    for (int c = 0; c < CH; ++c) {
        unsigned idx = (unsigned)(p * CH + c) * PSZ + i;
        unsigned v = hist[idx];
        hist[idx] = run;
        run += v;
    }
    deg[gid] = run;
}

// ---------- K1a: per-block degree sums ----------
__global__ void k_bsum(const unsigned* __restrict__ deg, unsigned* __restrict__ bsum) {
    __shared__ unsigned W[4];
    int t = threadIdx.x;
    int i = blockIdx.x * 256 + t;
    unsigned d = (i < NN) ? deg[i] : 0u;
    #pragma unroll
    for (int off = 1; off < 64; off <<= 1) d += __shfl_xor(d, off);
    if ((t & 63) == 0) W[t >> 6] = d;
    __syncthreads();
    if (t == 0) bsum[blockIdx.x] = W[0] + W[1] + W[2] + W[3];
}

// ---------- K1b: exclusive scan of block sums (1 block) ----------
__global__ __launch_bounds__(512) void k_bscan(unsigned* __restrict__ bsum) {
    __shared__ unsigned S[512];
    int t = threadIdx.x;
    unsigned v = (t < NBLK) ? bsum[t] : 0u;
    S[t] = v;
    __syncthreads();
    for (int off = 1; off < 512; off <<= 1) {
        unsigned u = (t >= off) ? S[t - off] : 0u;
        __syncthreads();
        S[t] += u;
        __syncthreads();
    }
    if (t < NBLK) bsum[t] = S[t] - v;   // exclusive prefix
}

// ---------- K1c: per-block scan -> cursor[i] = rowptr[i+1] (inclusive), dinv ----------
__global__ void k_cscan(const unsigned* __restrict__ deg, const unsigned* __restrict__ bsum,
                        unsigned* __restrict__ cursor, float* __restrict__ dinv) {
    __shared__ unsigned S[256];
    int t = threadIdx.x;
    int i = blockIdx.x * 256 + t;
    unsigned d = (i < NN) ? deg[i] : 0u;
    S[t] = d;
    __syncthreads();
    for (int off = 1; off < 256; off <<= 1) {
        unsigned u = (t >= off) ? S[t - off] : 0u;
        __syncthreads();
        S[t] += u;
        __syncthreads();
    }
    if (i < NN) {
        cursor[i] = bsum[blockIdx.x] + S[t];       // inclusive = rowptr[i+1]
        dinv[i] = rsqrtf((float)(d + 1u));
    }
}

// ---------- K2: place edges via LDS cursors (no global atomics) ----------
__global__ __launch_bounds__(256) void k_place(const unsigned* __restrict__ pbase,
                                               const unsigned* __restrict__ pcnt,
                                               const int* __restrict__ dpart,
                                               const int* __restrict__ spart,
                                               const unsigned* __restrict__ hist,
                                               const unsigned* __restrict__ cursor,
                                               int* __restrict__ ecol) {
    __shared__ unsigned lcur[PSZ];
    int p = blockIdx.x & 7;
    int c = blockIdx.x >> 3;
    int t = threadIdx.x;
    int pb = p * PSZ;
    const unsigned* hrow = hist + (unsigned)(p * CH + c) * PSZ;
    for (int i = t; i < PSZ; i += 256) {
        int gi = pb + i;
        unsigned rowstart = gi ? cursor[gi - 1] : 0u;
        lcur[i] = rowstart + hrow[i];
    }
    __syncthreads();
    unsigned s = pbase[p], n = pcnt[p];
    unsigned c0 = s + (unsigned)(((unsigned long long)n * c) / CH);
    unsigned c1 = s + (unsigned)(((unsigned long long)n * (c + 1)) / CH);
    for (unsigned j = c0 + t; j < c1; j += 256) {
        int dst = dpart[j];
        int src = spart[j];
        unsigned pos = atomicAdd(&lcur[dst - pb], 1u);
        ecol[pos] = src;
    }
}

// ---------- K3: h1h = fp16((X @ W1) * dinv[row]) — 128 rows/block, 4 blocks/CU ----------
__global__ __launch_bounds__(256) void k_gemm1(const float* __restrict__ X,
                                               const float* __restrict__ W1,
                                               const float* __restrict__ dinv,
                                               __half2* __restrict__ h1h) {
    __shared__ float Xs[32][129];
    __shared__ float4 Ws[1024];
    int tid = threadIdx.x;
    const float4* W14 = (const float4*)W1;
    for (int i = tid; i < 1024; i += 256) Ws[i] = W14[i];

    int rowbase = blockIdx.x * 128;
    int q  = tid >> 2;      // 0..63
    int cg = tid & 3;       // col group
    float4 acc[2] = {};

    for (int kt = 0; kt < 8; ++kt) {
        __syncthreads();
        // stage 128 rows x 32 k (512 float4, 2 per thread)
        #pragma unroll
        for (int it = 0; it < 2; ++it) {
            int fl = tid + it * 256;       // 0..511
            int rl = fl >> 2;              // 0..127
            int c4 = (fl & 3) << 3;        // 0,8,16,24
            int gr = rowbase + rl;
            float4 v0 = make_float4(0.f, 0.f, 0.f, 0.f);
            float4 v1 = v0;
            if (gr < NN) {
                v0 = *(const float4*)(X + (size_t)gr * FIN + kt * 32 + c4);
                v1 = *(const float4*)(X + (size_t)gr * FIN + kt * 32 + c4 + 4);
            }
            Xs[c4 + 0][rl] = v0.x;
            Xs[c4 + 1][rl] = v0.y;
            Xs[c4 + 2][rl] = v0.z;
            Xs[c4 + 3][rl] = v0.w;
            Xs[c4 + 4][rl] = v1.x;
            Xs[c4 + 5][rl] = v1.y;
            Xs[c4 + 6][rl] = v1.z;
            Xs[c4 + 7][rl] = v1.w;
        }
        __syncthreads();
        #pragma unroll
        for (int kk = 0; kk < 32; ++kk) {
            float4 w4 = Ws[(kt * 32 + kk) * 4 + cg];
            #pragma unroll
            for (int m = 0; m < 2; ++m) {
                float xv = Xs[kk][q + 64 * m];
                acc[m].x += xv * w4.x;
                acc[m].y += xv * w4.y;
                acc[m].z += xv * w4.z;
                acc[m].w += xv * w4.w;
            }
        }
    }
    #pragma unroll
    for (int m = 0; m < 2; ++m) {
        int r = rowbase + q + 64 * m;
        if (r < NN) {
            float dv = dinv[r];
            union { __half2 h[2]; uint2 u; } pk;
            pk.h[0] = __floats2half2_rn(acc[m].x * dv, acc[m].y * dv);
            pk.h[1] = __floats2half2_rn(acc[m].z * dv, acc[m].w * dv);
            *(uint2*)(h1h + (size_t)r * 8 + cg * 2) = pk.u;
        }
    }
}

// ---------- K4: fused gather-1 + gemm2 (fp16 in/out, f32 accumulate) ----------
// One node per wave; 8 lane-groups of 8; lane handles a half2 (2 features).
__global__ __launch_bounds__(256) void k_gathm(const unsigned* __restrict__ cursor,
                                               const int* __restrict__ ecol,
                                               const float* __restrict__ dinv,
                                               const float* __restrict__ b1,
                                               const float* __restrict__ W2,
                                               const __half2* __restrict__ h1h,
                                               __half2* __restrict__ h2h) {
    __shared__ float Ws[512];   // W2 [16][32]
    __shared__ float B1[16];
    int tid = threadIdx.x;
    Ws[tid] = W2[tid];
    Ws[tid + 256] = W2[tid + 256];
    if (tid < 16) B1[tid] = b1[tid];
    __syncthreads();
    int node = blockIdx.x * 4 + (tid >> 6);
    if (node >= NN) return;
    int lane = tid & 63;
    int f2 = lane & 7, nb = lane >> 3;            // 8 neighbor groups, stride 8
    unsigned s = node ? cursor[node - 1] : 0u;
    unsigned e = cursor[node];
    float2 acc = make_float2(0.f, 0.f);
    if (nb == 0) acc = __half22float2(h1h[(size_t)node * 8 + f2]);
    unsigned j = s + nb;
    while (j + 24 < e) {        // 4 rows in flight per group (32/wave)
        int c0 = ecol[j], c1 = ecol[j + 8], c2 = ecol[j + 16], c3 = ecol[j + 24];
        float2 a0 = __half22float2(h1h[(size_t)c0 * 8 + f2]);
        float2 a1 = __half22float2(h1h[(size_t)c1 * 8 + f2]);
        float2 a2 = __half22float2(h1h[(size_t)c2 * 8 + f2]);
        float2 a3 = __half22float2(h1h[(size_t)c3 * 8 + f2]);
        acc.x += (a0.x + a1.x) + (a2.x + a3.x);
        acc.y += (a0.y + a1.y) + (a2.y + a3.y);
        j += 32;
    }
    for (; j < e; j += 8) {
        float2 a = __half22float2(h1h[(size_t)ecol[j] * 8 + f2]);
        acc.x += a.x; acc.y += a.y;
    }
    acc.x += __shfl_xor(acc.x, 8);  acc.y += __shfl_xor(acc.y, 8);
    acc.x += __shfl_xor(acc.x, 16); acc.y += __shfl_xor(acc.y, 16);
    acc.x += __shfl_xor(acc.x, 32); acc.y += __shfl_xor(acc.y, 32);
    float dv = dinv[node];
    float r0 = fmaxf(acc.x * dv + B1[2 * f2], 0.f);
    float r1 = fmaxf(acc.y * dv + B1[2 * f2 + 1], 0.f);
    float rv[16];
    #pragma unroll
    for (int q = 0; q < 8; ++q) {
        rv[2 * q]     = __shfl(r0, q);
        rv[2 * q + 1] = __shfl(r1, q);
    }
    if (lane < 16) {
        float a0 = 0.f, a1 = 0.f;
        #pragma unroll
        for (int q = 0; q < 16; ++q) {
            a0 += rv[q] * Ws[q * 32 + 2 * lane];
            a1 += rv[q] * Ws[q * 32 + 2 * lane + 1];
        }
        h2h[(size_t)node * 16 + lane] = __floats2half2_rn(a0 * dv, a1 * dv);
    }
}

// ---------- K6: gather layer 2 (fp16 in, f32 out) ----------
// One node per wave; 4 lane-groups of 16; lane handles a half2.
__global__ __launch_bounds__(256) void k_gath2(const unsigned* __restrict__ cursor,
                                               const int* __restrict__ ecol,
                                               const float* __restrict__ dinv,
                                               const float* __restrict__ b2,
                                               const __half2* __restrict__ h2h,
                                               float* __restrict__ out2) {
    int tid = threadIdx.x;
    int node = blockIdx.x * 4 + (tid >> 6);
    if (node >= NN) return;
    int lane = tid & 63;
    int f2 = lane & 15, nb = lane >> 4;           // 4 neighbor groups, stride 4
    unsigned s = node ? cursor[node - 1] : 0u;
    unsigned e = cursor[node];
    float2 acc = make_float2(0.f, 0.f);
    if (nb == 0) acc = __half22float2(h2h[(size_t)node * 16 + f2]);
    unsigned j = s + nb;
    while (j + 12 < e) {        // 4 rows in flight per group (16/wave)
        int c0 = ecol[j], c1 = ecol[j + 4], c2 = ecol[j + 8], c3 = ecol[j + 12];
        float2 a0 = __half22float2(h2h[(size_t)c0 * 16 + f2]);
        float2 a1 = __half22float2(h2h[(size_t)c1 * 16 + f2]);
        float2 a2 = __half22float2(h2h[(size_t)c2 * 16 + f2]);
        float2 a3 = __half22float2(h2h[(size_t)c3 * 16 + f2]);
        acc.x += (a0.x + a1.x) + (a2.x + a3.x);
        acc.y += (a0.y + a1.y) + (a2.y + a3.y);
        j += 16;
    }
    for (; j < e; j += 4) {
        float2 a = __half22float2(h2h[(size_t)ecol[j] * 16 + f2]);
        acc.x += a.x; acc.y += a.y;
    }
    acc.x += __shfl_xor(acc.x, 16); acc.y += __shfl_xor(acc.y, 16);
    acc.x += __shfl_xor(acc.x, 32); acc.y += __shfl_xor(acc.y, 32);
    if (lane < 16) {
        float dv = dinv[node];
        float2 b = ((const float2*)b2)[f2];
        ((float2*)(out2 + (size_t)node * F2))[f2] =
            make_float2(acc.x * dv + b.x, acc.y * dv + b.y);
    }
}

// ---------- K7: conv1d(32->64, k=3, pad 1) + global max ----------
#define NPB 256
__global__ __launch_bounds__(256) void k_conv(const float* __restrict__ h2f,
                                              const float* __restrict__ cw,
                                              unsigned* __restrict__ pool) {
    __shared__ float Hs[NPB + 2][33];
    __shared__ float Wt[3 * 32 * 64];
    __shared__ float4 Ms[4][16];
    int tid = threadIdx.x;
    int base = blockIdx.x * NPB;
    for (int idx = tid; idx < 6144; idx += 256) {
        int o = idx / 96, r = idx % 96, ci = r / 3, k = r % 3;
        Wt[(k * 32 + ci) * 64 + o] = cw[idx];
    }
    for (int idx = tid; idx < (NPB + 2) * 8; idx += 256) {
        int j = idx >> 3, c4 = (idx & 7) << 2;
        int g = base + j - 1;
        float4 v = make_float4(0.f, 0.f, 0.f, 0.f);
        if (g >= 0 && g < NN) v = *(const float4*)(h2f + (size_t)g * F2 + c4);
        Hs[j][c4 + 0] = v.x;
        Hs[j][c4 + 1] = v.y;
        Hs[j][c4 + 2] = v.z;
        Hs[j][c4 + 3] = v.w;
    }
    __syncthreads();

    int o4 = (tid & 15) * 4;
    int ng = tid >> 4;
    float4 acc[16] = {};
    for (int ci = 0; ci < 32; ++ci) {
        float h[18];
        #pragma unroll
        for (int j = 0; j < 18; ++j) h[j] = Hs[ng * 16 + j][ci];
        #pragma unroll
        for (int k = 0; k < 3; ++k) {
            float4 w = *(const float4*)&Wt[(k * 32 + ci) * 64 + o4];
            #pragma unroll
            for (int i = 0; i < 16; ++i) {
                float hv = h[i + k];
                acc[i].x += hv * w.x;
                acc[i].y += hv * w.y;
                acc[i].z += hv * w.z;
                acc[i].w += hv * w.w;
            }
        }
    }
    const float NI = -3.0e38f;
    float4 m4 = make_float4(NI, NI, NI, NI);
    #pragma unroll
    for (int i = 0; i < 16; ++i) {
        if (base + ng * 16 + i < NN) {
            m4.x = fmaxf(m4.x, acc[i].x);
            m4.y = fmaxf(m4.y, acc[i].y);
            m4.z = fmaxf(m4.z, acc[i].z);
            m4.w = fmaxf(m4.w, acc[i].w);
        }
    }
    #pragma unroll
    for (int off = 16; off <= 32; off <<= 1) {
        m4.x = fmaxf(m4.x, __shfl_xor(m4.x, off));
        m4.y = fmaxf(m4.y, __shfl_xor(m4.y, off));
        m4.z = fmaxf(m4.z, __shfl_xor(m4.z, off));
        m4.w = fmaxf(m4.w, __shfl_xor(m4.w, off));
    }
    int lane = tid & 63, wv = tid >> 6;
    if (lane < 16) Ms[wv][lane] = m4;
    __syncthreads();
    if (tid < 16) {
        float4 a = Ms[0][tid], b = Ms[1][tid], c = Ms[2][tid], d = Ms[3][tid];
        a.x = fmaxf(fmaxf(a.x, b.x), fmaxf(c.x, d.x));
        a.y = fmaxf(fmaxf(a.y, b.y), fmaxf(c.y, d.y));
        a.z = fmaxf(fmaxf(a.z, b.z), fmaxf(c.z, d.z));
        a.w = fmaxf(fmaxf(a.w, b.w), fmaxf(c.w, d.w));
        int o = tid * 4;
        atomicMax(&pool[o + 0], enc_f(a.x));
        atomicMax(&pool[o + 1], enc_f(a.y));
        atomicMax(&pool[o + 2], enc_f(a.z));
        atomicMax(&pool[o + 3], enc_f(a.w));
    }
}

// ---------- K8: out = (pooled + conv_b) @ fc_w^T + fc_b ----------
__global__ void k_fc(const unsigned* __restrict__ pool, const float* __restrict__ cb,
                     const float* __restrict__ fw, const float* __restrict__ fb,
                     float* __restrict__ out) {
    __shared__ float P[64];
    int tid = threadIdx.x;
    if (tid < 64) P[tid] = dec_f(pool[tid]) + cb[tid];
    __syncthreads();
    int j = blockIdx.x * 256 + tid;
    if (j >= NC) return;
    float s = fb[j];
    const float4* wr = (const float4*)(fw + (size_t)j * CO);
    #pragma unroll
    for (int c = 0; c < 16; ++c) {
        float4 w = wr[c];
        s += P[c * 4 + 0] * w.x + P[c * 4 + 1] * w.y +
             P[c * 4 + 2] * w.z + P[c * 4 + 3] * w.w;
    }
    out[j] = s;
}

extern "C" void kernel_launch(void* const* d_in, const int* in_sizes, int n_in,
                              void* d_out, int out_size, void* d_ws, size_t ws_size,
                              hipStream_t stream) {
    const float* x  = (const float*)d_in[0];
    const int*   ei = (const int*)d_in[1];
    const float* W1 = (const float*)d_in[2];
    const float* b1 = (const float*)d_in[3];
    const float* W2 = (const float*)d_in[4];
    const float* b2 = (const float*)d_in[5];
    const float* cw = (const float*)d_in[6];
    const float* cb = (const float*)d_in[7];
    const float* fw = (const float*)d_in[8];
    const float* fb = (const float*)d_in[9];

    float* ws = (float*)d_ws;
    float*    dinv   = ws + OFF_DINV;
    unsigned* cursor = (unsigned*)(ws + OFF_CUR);
    unsigned* deg    = (unsigned*)(ws + OFF_DEG);
    int*      ecol   = (int*)(ws + OFF_ECOL);
    unsigned* pcnt   = (unsigned*)(ws + OFF_MISC);
    unsigned* pbase  = pcnt + 8;
    unsigned* pcur   = pcnt + 16;
    unsigned* pool   = pcnt + 64;
    unsigned* bsum   = pcnt + 512;
    int*      dpart  = (int*)(ws + OFF_DPART);
    int*      spart  = (int*)(ws + OFF_SPART);
    unsigned* hist   = (unsigned*)(ws + OFF_HIST);
    __half2*  h1h    = (__half2*)(ws + OFF_H1S);
    __half2*  h2h    = (__half2*)(ws + OFF_H2S);
    float*    out2   = ws + OFF_OUT2;

    hipMemsetAsync(pcnt, 0, 8 * 4, stream);
    hipMemsetAsync(pool, 0, 64 * 4, stream);

    k_pcount <<<NE / (256 * BK), 256, 0, stream>>>(ei, pcnt);          // 625 blocks
    k_pscan  <<<1, 64, 0, stream>>>(pcnt, pbase, pcur);
    k_bucket <<<NE / (256 * BK), 256, 0, stream>>>(ei, pcur, dpart, spart);
    k_hist   <<<CH * NPART, 256, 0, stream>>>(pbase, pcnt, dpart, hist);   // 128 blocks
    k_colscan<<<NBLK, 256, 0, stream>>>(hist, deg);
    k_bsum   <<<NBLK, 256, 0, stream>>>(deg, bsum);
    k_bscan  <<<1, 512, 0, stream>>>(bsum);
    k_cscan  <<<NBLK, 256, 0, stream>>>(deg, bsum, cursor, dinv);
    k_place  <<<CH * NPART, 256, 0, stream>>>(pbase, pcnt, dpart, spart, hist, cursor, ecol);
    k_gemm1  <<<GBLK, 256, 0, stream>>>(x, W1, dinv, h1h);
    k_gathm  <<<(NN + 3) / 4, 256, 0, stream>>>(cursor, ecol, dinv, b1, W2, h1h, h2h);
    k_gath2  <<<(NN + 3) / 4, 256, 0, stream>>>(cursor, ecol, dinv, b2, h2h, out2);
    k_conv   <<<(NN + NPB - 1) / NPB, 256, 0, stream>>>(out2, cw, pool);
    k_fc     <<<4, 256, 0, stream>>>(pool, cb, fw, fb, (float*)d_out);
}

// Round 11
// 360.718 us; speedup vs baseline: 1.1845x; 1.0709x over previous
//
#include <hip/hip_runtime.h>
#include <hip/hip_bf16.h>
#include <hip/hip_fp16.h>

#define NN 100000
#define NE 3200000
#define FIN 256
#define F1 16
#define F2 32
#define CO 64
#define NC 1000
#define NBLK 391   /* ceil(NN/256) */
#define GBLK 782   /* ceil(NN/128) gemm1 grid */
#define NPART 8
#define PSZ 12500  /* NN / NPART */
#define BK 20      /* edges per thread in pcount/bucket; 625 blocks * 256 * 20 = NE */
#define CH 16      /* chunks per partition for hist/place */

// workspace layout (float offsets) — total 11,502,080 floats = 46.0 MB
#define OFF_DINV 0
#define OFF_CUR  100352
#define OFF_DEG  200704
#define OFF_ECOL 301056
#define OFF_MISC 3501056   /* pcnt[8], pbase[8], pcur[8], pool[64]@64, bsum[512]@512 */
#define OFF_DPART 3502080
#define OFF_SPART 6702080
#define OFF_HIST 9902080   /* u32[NPART*CH*PSZ] = 1.6M */
#define OFF_H1S  3502080   /* fp16, 800K floats; overlays dpart (dead after place) */
#define OFF_H2S  6702080   /* fp16, 1.6M floats (ends 8302080); overlays spart (dead after place) */
#define OFF_OUT2 3502080   /* f32 3.2M floats: 3502080..6702080 — overlays h1h+dpart (dead
                              after gathm), ends exactly at h2h start. MUST NOT cross 6702080. */

__device__ __forceinline__ unsigned enc_f(float f) {
    unsigned u = __float_as_uint(f);
    return (u & 0x80000000u) ? ~u : (u | 0x80000000u);
}
__device__ __forceinline__ float dec_f(unsigned u) {
    return (u & 0x80000000u) ? __uint_as_float(u & 0x7fffffffu) : __uint_as_float(~u);
}

// ---------- K0a: partition edge counts (ballot-based, no LDS) ----------
__global__ __launch_bounds__(256) void k_pcount(const int* __restrict__ ei,
                                                unsigned* __restrict__ pcnt) {
    int t = threadIdx.x, lane = t & 63;
    int base = blockIdx.x * (256 * BK) + t;
    unsigned cnt = 0;
    #pragma unroll
    for (int k = 0; k < BK; ++k) {
        int bin = (unsigned)ei[NE + base + k * 256] / PSZ;
        #pragma unroll
        for (int b = 0; b < 8; ++b) {
            unsigned long long m = __ballot(bin == b);
            if (lane == b) cnt += (unsigned)__popcll(m);
        }
    }
    if (lane < 8) atomicAdd(&pcnt[lane], cnt);
}

// ---------- K0b: 8-way exclusive prefix -> pbase, pcur ----------
__global__ void k_pscan(const unsigned* __restrict__ pcnt, unsigned* __restrict__ pbase,
                        unsigned* __restrict__ pcur) {
    int t = threadIdx.x;
    if (t < 8) {
        unsigned v = 0;
        for (int i = 0; i < t; ++i) v += pcnt[i];
        pbase[t] = v;
        pcur[t] = v;
    }
}

// ---------- K0c: bucket edges into partition-segmented (dst,src) arrays ----------
__global__ __launch_bounds__(256) void k_bucket(const int* __restrict__ ei,
                                                unsigned* __restrict__ pcur,
                                                int* __restrict__ dpart,
                                                int* __restrict__ spart) {
    int t = threadIdx.x, lane = t & 63;
    int base = blockIdx.x * (256 * BK) + t;
    int dst[BK], src[BK];
    #pragma unroll
    for (int k = 0; k < BK; ++k) {
        dst[k] = ei[NE + base + k * 256];
        src[k] = ei[base + k * 256];
    }
    unsigned long long lt = (lane == 63) ? 0x7fffffffffffffffull
                                         : ((1ull << lane) - 1ull);
    unsigned cnt = 0;
    #pragma unroll
    for (int k = 0; k < BK; ++k) {
        int bin = (unsigned)dst[k] / PSZ;
        #pragma unroll
        for (int b = 0; b < 8; ++b) {
            unsigned long long m = __ballot(bin == b);
            if (lane == b) cnt += (unsigned)__popcll(m);
        }
    }
    unsigned run = 0;
    if (lane < 8) run = atomicAdd(&pcur[lane], cnt);
    #pragma unroll
    for (int k = 0; k < BK; ++k) {
        int bin = (unsigned)dst[k] / PSZ;
        unsigned long long mym = 0;
        unsigned myrun = 0;
        #pragma unroll
        for (int b = 0; b < 8; ++b) {
            unsigned long long m = __ballot(bin == b);
            unsigned r = __shfl(run, b);
            if (bin == b) { mym = m; myrun = r; }
            if (lane == b) run += (unsigned)__popcll(m);
        }
        unsigned pos = myrun + (unsigned)__popcll(mym & lt);
        dpart[pos] = dst[k];
        spart[pos] = src[k];
    }
}

// ---------- K0d: per-chunk LDS histograms -> hist[p][c][i] ----------
__global__ __launch_bounds__(256) void k_hist(const unsigned* __restrict__ pbase,
                                              const unsigned* __restrict__ pcnt,
                                              const int* __restrict__ dpart,
                                              unsigned* __restrict__ hist) {
    __shared__ unsigned lh[PSZ];
    int p = blockIdx.x & 7;
    int c = blockIdx.x >> 3;               // 0..CH-1
    int t = threadIdx.x;
    for (int i = t; i < PSZ; i += 256) lh[i] = 0;
    __syncthreads();
    unsigned s = pbase[p], n = pcnt[p];
    unsigned c0 = s + (unsigned)(((unsigned long long)n * c) / CH);
    unsigned c1 = s + (unsigned)(((unsigned long long)n * (c + 1)) / CH);
    int pb = p * PSZ;
    for (unsigned j = c0 + t; j < c1; j += 256)
        atomicAdd(&lh[dpart[j] - pb], 1u);
    __syncthreads();
    unsigned* hrow = hist + (unsigned)(p * CH + c) * PSZ;
    for (int i = t; i < PSZ; i += 256) hrow[i] = lh[i];
}

// ---------- K0e: scan chunk counts per bin -> chunk bases (in place) + deg ----------
__global__ __launch_bounds__(256) void k_colscan(unsigned* __restrict__ hist,
                                                 unsigned* __restrict__ deg) {
    int gid = blockIdx.x * 256 + threadIdx.x;
    if (gid >= NN) return;
    int p = gid / PSZ, i = gid % PSZ;
    unsigned run = 0;
    #pragma unroll
    for (int c = 0; c < CH; ++c) {
        unsigned idx = (unsigned)(p * CH + c) * PSZ + i;
        unsigned v = hist[idx];
        hist[idx] = run;
        run += v;
    }
    deg[gid] = run;
}

// ---------- K1a: per-block degree sums ----------
__global__ void k_bsum(const unsigned* __restrict__ deg, unsigned* __restrict__ bsum) {
    __shared__ unsigned W[4];
    int t = threadIdx.x;
    int i = blockIdx.x * 256 + t;
    unsigned d = (i < NN) ? deg[i] : 0u;
    #pragma unroll
    for (int off = 1; off < 64; off <<= 1) d += __shfl_xor(d, off);
    if ((t & 63) == 0) W[t >> 6] = d;
    __syncthreads();
    if (t == 0) bsum[blockIdx.x] = W[0] + W[1] + W[2] + W[3];
}

// ---------- K1b: exclusive scan of block sums (1 block) ----------
__global__ __launch_bounds__(512) void k_bscan(unsigned* __restrict__ bsum) {
    __shared__ unsigned S[512];
    int t = threadIdx.x;
    unsigned v = (t < NBLK) ? bsum[t] : 0u;
    S[t] = v;
    __syncthreads();
    for (int off = 1; off < 512; off <<= 1) {
        unsigned u = (t >= off) ? S[t - off] : 0u;
        __syncthreads();
        S[t] += u;
        __syncthreads();
    }
    if (t < NBLK) bsum[t] = S[t] - v;   // exclusive prefix
}

// ---------- K1c: per-block scan -> cursor[i] = rowptr[i+1] (inclusive), dinv ----------
__global__ void k_cscan(const unsigned* __restrict__ deg, const unsigned* __restrict__ bsum,
                        unsigned* __restrict__ cursor, float* __restrict__ dinv) {
    __shared__ unsigned S[256];
    int t = threadIdx.x;
    int i = blockIdx.x * 256 + t;
    unsigned d = (i < NN) ? deg[i] : 0u;
    S[t] = d;
    __syncthreads();
    for (int off = 1; off < 256; off <<= 1) {
        unsigned u = (t >= off) ? S[t - off] : 0u;
        __syncthreads();
        S[t] += u;
        __syncthreads();
    }
    if (i < NN) {
        cursor[i] = bsum[blockIdx.x] + S[t];       // inclusive = rowptr[i+1]
        dinv[i] = rsqrtf((float)(d + 1u));
    }
}

// ---------- K2: place edges via LDS cursors (no global atomics) ----------
__global__ __launch_bounds__(256) void k_place(const unsigned* __restrict__ pbase,
                                               const unsigned* __restrict__ pcnt,
                                               const int* __restrict__ dpart,
                                               const int* __restrict__ spart,
                                               const unsigned* __restrict__ hist,
                                               const unsigned* __restrict__ cursor,
                                               int* __restrict__ ecol) {
    __shared__ unsigned lcur[PSZ];
    int p = blockIdx.x & 7;
    int c = blockIdx.x >> 3;
    int t = threadIdx.x;
    int pb = p * PSZ;
    const unsigned* hrow = hist + (unsigned)(p * CH + c) * PSZ;
    for (int i = t; i < PSZ; i += 256) {
        int gi = pb + i;
        unsigned rowstart = gi ? cursor[gi - 1] : 0u;
        lcur[i] = rowstart + hrow[i];
    }
    __syncthreads();
    unsigned s = pbase[p], n = pcnt[p];
    unsigned c0 = s + (unsigned)(((unsigned long long)n * c) / CH);
    unsigned c1 = s + (unsigned)(((unsigned long long)n * (c + 1)) / CH);
    for (unsigned j = c0 + t; j < c1; j += 256) {
        int dst = dpart[j];
        int src = spart[j];
        unsigned pos = atomicAdd(&lcur[dst - pb], 1u);
        ecol[pos] = src;
    }
}

// ---------- K3: h1h = fp16((X @ W1) * dinv[row]) — 128 rows/block, 4 blocks/CU ----------
__global__ __launch_bounds__(256) void k_gemm1(const float* __restrict__ X,
                                               const float* __restrict__ W1,
                                               const float* __restrict__ dinv,
                                               __half2* __restrict__ h1h) {
    __shared__ float Xs[32][129];
    __shared__ float4 Ws[1024];
    int tid = threadIdx.x;
    const float4* W14 = (const float4*)W1;
    for (int i = tid; i < 1024; i += 256) Ws[i] = W14[i];

    int rowbase = blockIdx.x * 128;
    int q  = tid >> 2;      // 0..63
    int cg = tid & 3;       // col group
    float4 acc[2] = {};

    for (int kt = 0; kt < 8; ++kt) {
        __syncthreads();
        // stage 128 rows x 32 k (512 float4, 2 per thread)
        #pragma unroll
        for (int it = 0; it < 2; ++it) {
            int fl = tid + it * 256;       // 0..511
            int rl = fl >> 2;              // 0..127
            int c4 = (fl & 3) << 3;        // 0,8,16,24
            int gr = rowbase + rl;
            float4 v0 = make_float4(0.f, 0.f, 0.f, 0.f);
            float4 v1 = v0;
            if (gr < NN) {
                v0 = *(const float4*)(X + (size_t)gr * FIN + kt * 32 + c4);
                v1 = *(const float4*)(X + (size_t)gr * FIN + kt * 32 + c4 + 4);
            }
            Xs[c4 + 0][rl] = v0.x;
            Xs[c4 + 1][rl] = v0.y;
            Xs[c4 + 2][rl] = v0.z;
            Xs[c4 + 3][rl] = v0.w;
            Xs[c4 + 4][rl] = v1.x;
            Xs[c4 + 5][rl] = v1.y;
            Xs[c4 + 6][rl] = v1.z;
            Xs[c4 + 7][rl] = v1.w;
        }
        __syncthreads();
        #pragma unroll
        for (int kk = 0; kk < 32; ++kk) {
            float4 w4 = Ws[(kt * 32 + kk) * 4 + cg];
            #pragma unroll
            for (int m = 0; m < 2; ++m) {
                float xv = Xs[kk][q + 64 * m];
                acc[m].x += xv * w4.x;
                acc[m].y += xv * w4.y;
                acc[m].z += xv * w4.z;
                acc[m].w += xv * w4.w;
            }
        }
    }
    #pragma unroll
    for (int m = 0; m < 2; ++m) {
        int r = rowbase + q + 64 * m;
        if (r < NN) {
            float dv = dinv[r];
            union { __half2 h[2]; uint2 u; } pk;
            pk.h[0] = __floats2half2_rn(acc[m].x * dv, acc[m].y * dv);
            pk.h[1] = __floats2half2_rn(acc[m].z * dv, acc[m].w * dv);
            *(uint2*)(h1h + (size_t)r * 8 + cg * 2) = pk.u;
        }
    }
}

// ---------- K4: fused gather-1 + gemm2 — node per 8-lane group (8 nodes/wave) ----------
// Lane f2 owns one half2; accumulates ALL edges of its group's node -> no reduce.
// 3125 blocks * 32 nodes = 100000 exactly.
__global__ __launch_bounds__(256) void k_gathm(const unsigned* __restrict__ cursor,
                                               const int* __restrict__ ecol,
                                               const float* __restrict__ dinv,
                                               const float* __restrict__ b1,
                                               const float* __restrict__ W2,
                                               const __half2* __restrict__ h1h,
                                               __half2* __restrict__ h2h) {
    __shared__ float Ws[512];   // W2 [16][32]
    __shared__ float B1[16];
    int tid = threadIdx.x;
    Ws[tid] = W2[tid];
    Ws[tid + 256] = W2[tid + 256];
    if (tid < 16) B1[tid] = b1[tid];
    __syncthreads();
    int lane = tid & 63;
    int grp = lane >> 3, f2 = lane & 7;
    int node = blockIdx.x * 32 + (tid >> 6) * 8 + grp;
    unsigned s = node ? cursor[node - 1] : 0u;
    unsigned e = cursor[node];
    float2 acc = __half22float2(h1h[(size_t)node * 8 + f2]);   // self term
    for (unsigned j = s; j < e; j += 4) {
        bool v1 = j + 1 < e, v2 = j + 2 < e, v3 = j + 3 < e;
        int c0 = ecol[j];
        int c1 = v1 ? ecol[j + 1] : c0;
        int c2 = v2 ? ecol[j + 2] : c0;
        int c3 = v3 ? ecol[j + 3] : c0;
        float2 a0 = __half22float2(h1h[(size_t)c0 * 8 + f2]);
        float2 a1 = __half22float2(h1h[(size_t)c1 * 8 + f2]);
        float2 a2 = __half22float2(h1h[(size_t)c2 * 8 + f2]);
        float2 a3 = __half22float2(h1h[(size_t)c3 * 8 + f2]);
        float m1 = v1 ? 1.f : 0.f, m2 = v2 ? 1.f : 0.f, m3 = v3 ? 1.f : 0.f;
        acc.x += a0.x + m1 * a1.x + m2 * a2.x + m3 * a3.x;
        acc.y += a0.y + m1 * a1.y + m2 * a2.y + m3 * a3.y;
    }
    float dv = dinv[node];
    float r0 = fmaxf(acc.x * dv + B1[2 * f2], 0.f);
    float r1 = fmaxf(acc.y * dv + B1[2 * f2 + 1], 0.f);
    // gather the group's 16 r-values (group-local shuffles, all lanes active)
    int gb = lane & 56;
    float rv[16];
    #pragma unroll
    for (int q = 0; q < 8; ++q) {
        rv[2 * q]     = __shfl(r0, gb + q);
        rv[2 * q + 1] = __shfl(r1, gb + q);
    }
    // each lane computes output half2 indices {f2, f2+8}
    float o0x = 0.f, o0y = 0.f, o1x = 0.f, o1y = 0.f;
    #pragma unroll
    for (int q = 0; q < 16; ++q) {
        float r = rv[q];
        o0x += r * Ws[q * 32 + 2 * f2];
        o0y += r * Ws[q * 32 + 2 * f2 + 1];
        o1x += r * Ws[q * 32 + 2 * f2 + 16];
        o1y += r * Ws[q * 32 + 2 * f2 + 17];
    }
    h2h[(size_t)node * 16 + f2]     = __floats2half2_rn(o0x * dv, o0y * dv);
    h2h[(size_t)node * 16 + f2 + 8] = __floats2half2_rn(o1x * dv, o1y * dv);
}

// ---------- K6: gather layer 2 — node per 16-lane group (4 nodes/wave) ----------
// 6250 blocks * 16 nodes = 100000 exactly.
__global__ __launch_bounds__(256) void k_gath2(const unsigned* __restrict__ cursor,
                                               const int* __restrict__ ecol,
                                               const float* __restrict__ dinv,
                                               const float* __restrict__ b2,
                                               const __half2* __restrict__ h2h,
                                               float* __restrict__ out2) {
    int tid = threadIdx.x;
    int lane = tid & 63;
    int grp = lane >> 4, f2 = lane & 15;
    int node = blockIdx.x * 16 + (tid >> 6) * 4 + grp;
    unsigned s = node ? cursor[node - 1] : 0u;
    unsigned e = cursor[node];
    float2 acc = __half22float2(h2h[(size_t)node * 16 + f2]);  // self term
    for (unsigned j = s; j < e; j += 4) {
        bool v1 = j + 1 < e, v2 = j + 2 < e, v3 = j + 3 < e;
        int c0 = ecol[j];
        int c1 = v1 ? ecol[j + 1] : c0;
        int c2 = v2 ? ecol[j + 2] : c0;
        int c3 = v3 ? ecol[j + 3] : c0;
        float2 a0 = __half22float2(h2h[(size_t)c0 * 16 + f2]);
        float2 a1 = __half22float2(h2h[(size_t)c1 * 16 + f2]);
        float2 a2 = __half22float2(h2h[(size_t)c2 * 16 + f2]);
        float2 a3 = __half22float2(h2h[(size_t)c3 * 16 + f2]);
        float m1 = v1 ? 1.f : 0.f, m2 = v2 ? 1.f : 0.f, m3 = v3 ? 1.f : 0.f;
        acc.x += a0.x + m1 * a1.x + m2 * a2.x + m3 * a3.x;
        acc.y += a0.y + m1 * a1.y + m2 * a2.y + m3 * a3.y;
    }
    float dv = dinv[node];
    float2 b = ((const float2*)b2)[f2];
    ((float2*)(out2 + (size_t)node * F2))[f2] =
        make_float2(acc.x * dv + b.x, acc.y * dv + b.y);
}

// ---------- K7: conv1d(32->64, k=3, pad 1) + global max ----------
#define NPB 256
__global__ __launch_bounds__(256) void k_conv(const float* __restrict__ h2f,
                                              const float* __restrict__ cw,
                                              unsigned* __restrict__ pool) {
    __shared__ float Hs[NPB + 2][33];
    __shared__ float Wt[3 * 32 * 64];
    __shared__ float4 Ms[4][16];
    int tid = threadIdx.x;
    int base = blockIdx.x * NPB;
    for (int idx = tid; idx < 6144; idx += 256) {
        int o = idx / 96, r = idx % 96, ci = r / 3, k = r % 3;
        Wt[(k * 32 + ci) * 64 + o] = cw[idx];
    }
    for (int idx = tid; idx < (NPB + 2) * 8; idx += 256) {
        int j = idx >> 3, c4 = (idx & 7) << 2;
        int g = base + j - 1;
        float4 v = make_float4(0.f, 0.f, 0.f, 0.f);
        if (g >= 0 && g < NN) v = *(const float4*)(h2f + (size_t)g * F2 + c4);
        Hs[j][c4 + 0] = v.x;
        Hs[j][c4 + 1] = v.y;
        Hs[j][c4 + 2] = v.z;
        Hs[j][c4 + 3] = v.w;
    }
    __syncthreads();

    int o4 = (tid & 15) * 4;
    int ng = tid >> 4;
    float4 acc[16] = {};
    for (int ci = 0; ci < 32; ++ci) {
        float h[18];
        #pragma unroll
        for (int j = 0; j < 18; ++j) h[j] = Hs[ng * 16 + j][ci];
        #pragma unroll
        for (int k = 0; k < 3; ++k) {
            float4 w = *(const float4*)&Wt[(k * 32 + ci) * 64 + o4];
            #pragma unroll
            for (int i = 0; i < 16; ++i) {
                float hv = h[i + k];
                acc[i].x += hv * w.x;
                acc[i].y += hv * w.y;
                acc[i].z += hv * w.z;
                acc[i].w += hv * w.w;
            }
        }
    }
    const float NI = -3.0e38f;
    float4 m4 = make_float4(NI, NI, NI, NI);
    #pragma unroll
    for (int i = 0; i < 16; ++i) {
        if (base + ng * 16 + i < NN) {
            m4.x = fmaxf(m4.x, acc[i].x);
            m4.y = fmaxf(m4.y, acc[i].y);
            m4.z = fmaxf(m4.z, acc[i].z);
            m4.w = fmaxf(m4.w, acc[i].w);
        }
    }
    #pragma unroll
    for (int off = 16; off <= 32; off <<= 1) {
        m4.x = fmaxf(m4.x, __shfl_xor(m4.x, off));
        m4.y = fmaxf(m4.y, __shfl_xor(m4.y, off));
        m4.z = fmaxf(m4.z, __shfl_xor(m4.z, off));
        m4.w = fmaxf(m4.w, __shfl_xor(m4.w, off));
    }
    int lane = tid & 63, wv = tid >> 6;
    if (lane < 16) Ms[wv][lane] = m4;
    __syncthreads();
    if (tid < 16) {
        float4 a = Ms[0][tid], b = Ms[1][tid], c = Ms[2][tid], d = Ms[3][tid];
        a.x = fmaxf(fmaxf(a.x, b.x), fmaxf(c.x, d.x));
        a.y = fmaxf(fmaxf(a.y, b.y), fmaxf(c.y, d.y));
        a.z = fmaxf(fmaxf(a.z, b.z), fmaxf(c.z, d.z));
        a.w = fmaxf(fmaxf(a.w, b.w), fmaxf(c.w, d.w));
        int o = tid * 4;
        atomicMax(&pool[o + 0], enc_f(a.x));
        atomicMax(&pool[o + 1], enc_f(a.y));
        atomicMax(&pool[o + 2], enc_f(a.z));
        atomicMax(&pool[o + 3], enc_f(a.w));
    }
}

// ---------- K8: out = (pooled + conv_b) @ fc_w^T + fc_b ----------
__global__ void k_fc(const unsigned* __restrict__ pool, const float* __restrict__ cb,
                     const float* __restrict__ fw, const float* __restrict__ fb,
                     float* __restrict__ out) {
    __shared__ float P[64];
    int tid = threadIdx.x;
    if (tid < 64) P[tid] = dec_f(pool[tid]) + cb[tid];
    __syncthreads();
    int j = blockIdx.x * 256 + tid;
    if (j >= NC) return;
    float s = fb[j];
    const float4* wr = (const float4*)(fw + (size_t)j * CO);
    #pragma unroll
    for (int c = 0; c < 16; ++c) {
        float4 w = wr[c];
        s += P[c * 4 + 0] * w.x + P[c * 4 + 1] * w.y +
             P[c * 4 + 2] * w.z + P[c * 4 + 3] * w.w;
    }
    out[j] = s;
}

extern "C" void kernel_launch(void* const* d_in, const int* in_sizes, int n_in,
                              void* d_out, int out_size, void* d_ws, size_t ws_size,
                              hipStream_t stream) {
    const float* x  = (const float*)d_in[0];
    const int*   ei = (const int*)d_in[1];
    const float* W1 = (const float*)d_in[2];
    const float* b1 = (const float*)d_in[3];
    const float* W2 = (const float*)d_in[4];
    const float* b2 = (const float*)d_in[5];
    const float* cw = (const float*)d_in[6];
    const float* cb = (const float*)d_in[7];
    const float* fw = (const float*)d_in[8];
    const float* fb = (const float*)d_in[9];

    float* ws = (float*)d_ws;
    float*    dinv   = ws + OFF_DINV;
    unsigned* cursor = (unsigned*)(ws + OFF_CUR);
    unsigned* deg    = (unsigned*)(ws + OFF_DEG);
    int*      ecol   = (int*)(ws + OFF_ECOL);
    unsigned* pcnt   = (unsigned*)(ws + OFF_MISC);
    unsigned* pbase  = pcnt + 8;
    unsigned* pcur   = pcnt + 16;
    unsigned* pool   = pcnt + 64;
    unsigned* bsum   = pcnt + 512;
    int*      dpart  = (int*)(ws + OFF_DPART);
    int*      spart  = (int*)(ws + OFF_SPART);
    unsigned* hist   = (unsigned*)(ws + OFF_HIST);
    __half2*  h1h    = (__half2*)(ws + OFF_H1S);
    __half2*  h2h    = (__half2*)(ws + OFF_H2S);
    float*    out2   = ws + OFF_OUT2;

    hipMemsetAsync(pcnt, 0, 8 * 4, stream);
    hipMemsetAsync(pool, 0, 64 * 4, stream);

    k_pcount <<<NE / (256 * BK), 256, 0, stream>>>(ei, pcnt);          // 625 blocks
    k_pscan  <<<1, 64, 0, stream>>>(pcnt, pbase, pcur);
    k_bucket <<<NE / (256 * BK), 256, 0, stream>>>(ei, pcur, dpart, spart);
    k_hist   <<<CH * NPART, 256, 0, stream>>>(pbase, pcnt, dpart, hist);   // 128 blocks
    k_colscan<<<NBLK, 256, 0, stream>>>(hist, deg);
    k_bsum   <<<NBLK, 256, 0, stream>>>(deg, bsum);
    k_bscan  <<<1, 512, 0, stream>>>(bsum);
    k_cscan  <<<NBLK, 256, 0, stream>>>(deg, bsum, cursor, dinv);
    k_place  <<<CH * NPART, 256, 0, stream>>>(pbase, pcnt, dpart, spart, hist, cursor, ecol);
    k_gemm1  <<<GBLK, 256, 0, stream>>>(x, W1, dinv, h1h);
    k_gathm  <<<NN / 32, 256, 0, stream>>>(cursor, ecol, dinv, b1, W2, h1h, h2h);   // 3125
    k_gath2  <<<NN / 16, 256, 0, stream>>>(cursor, ecol, dinv, b2, h2h, out2);      // 6250
    k_conv   <<<(NN + NPB - 1) / NPB, 256, 0, stream>>>(out2, cw, pool);
    k_fc     <<<4, 256, 0, stream>>>(pool, cb, fw, fb, (float*)d_out);
}